// Round 13
// baseline (480.627 us; speedup 1.0000x reference)
//
#include <hip/hip_runtime.h>
#include <math.h>

typedef __attribute__((ext_vector_type(2))) unsigned int uint2v;
typedef __attribute__((ext_vector_type(4))) int    int4v;
typedef __attribute__((ext_vector_type(4))) float  float4v;
typedef __attribute__((ext_vector_type(8))) __bf16 bf16x8;

#define SCAN_BLK 1024
#define EBLK 512

static constexpr float SELU_SCALE = 1.0507009873554805f;
static constexpr float SELU_ALPHA = 1.6732632423543772f;

__device__ __forceinline__ float selu_f(float x) {
    const float sa = SELU_SCALE * SELU_ALPHA;
    float e = __expf(x);
    return x > 0.0f ? SELU_SCALE * x : fmaf(sa, e, -sa);
}

// scalar RNE f32->bf16 (cold paths: wprep only)
__device__ __forceinline__ unsigned short f2bf(float f) {
    uint32_t u = __builtin_bit_cast(uint32_t, f);
    return (unsigned short)((u + 0x7FFFu + ((u >> 16) & 1u)) >> 16);
}

// HW packed convert: a -> bits[15:0], b -> bits[31:16], RNE.
__device__ __forceinline__ uint32_t pk2(float a, float b) {
    uint32_t r;
    asm("v_cvt_pk_bf16_f32 %0, %1, %2" : "=v"(r) : "v"(a), "v"(b));
    return r;
}

__device__ __forceinline__ float bflo(uint32_t u) {
    return __builtin_bit_cast(float, u << 16);
}
__device__ __forceinline__ float bfhi(uint32_t u) {
    return __builtin_bit_cast(float, u & 0xFFFF0000u);
}

__device__ __forceinline__ float4v mfma_bf16(int4v a, int4v b, float4v c) {
    return __builtin_amdgcn_mfma_f32_16x16x32_bf16(
        __builtin_bit_cast(bf16x8, a), __builtin_bit_cast(bf16x8, b), c, 0, 0, 0);
}

// ---------------- CSR build (count + scan; fill/permute fused into phi_e) -------------

__global__ __launch_bounds__(256) void cnt_kernel(const int* __restrict__ ba1,
                                                  int* __restrict__ cnt, int nb) {
    for (int e = blockIdx.x * 256 + threadIdx.x; e < nb; e += gridDim.x * 256)
        atomicAdd(cnt + ba1[e], 1);
}

__global__ __launch_bounds__(SCAN_BLK) void scan_block_kernel(const int* __restrict__ cnt,
                                                              int* __restrict__ excl,
                                                              int* __restrict__ bsums, int na) {
    __shared__ int tmp[SCAN_BLK];
    const int t = threadIdx.x;
    const int base = blockIdx.x * SCAN_BLK;
    const int v = (base + t < na) ? cnt[base + t] : 0;
    tmp[t] = v;
    __syncthreads();
    for (int off = 1; off < SCAN_BLK; off <<= 1) {
        const int add = (t >= off) ? tmp[t - off] : 0;
        __syncthreads();
        tmp[t] += add;
        __syncthreads();
    }
    if (base + t < na) excl[base + t] = tmp[t] - v;
    if (t == SCAN_BLK - 1) bsums[blockIdx.x] = tmp[t];
}

__global__ void scan_tops_kernel(const int* __restrict__ bsums, int* __restrict__ bases,
                                 int nblocks) {
    if (threadIdx.x == 0 && blockIdx.x == 0) {
        int s = 0;
        for (int bk = 0; bk < nblocks; ++bk) { bases[bk] = s; s += bsums[bk]; }
    }
}

__global__ __launch_bounds__(256) void wcur_init_kernel(const int* __restrict__ excl,
                                                        const int* __restrict__ bases,
                                                        int* __restrict__ wcur, int na) {
    const int a = blockIdx.x * 256 + threadIdx.x;
    if (a < na) wcur[a] = bases[a >> 10] + excl[a];
}

// ---------------- prep: fold state into layer-1 bias ----------------

__global__ void bias_prep_kernel(const float* __restrict__ state,
                                 const float* __restrict__ ew1, const float* __restrict__ eb1,
                                 const float* __restrict__ vw1, const float* __restrict__ vb1,
                                 float* __restrict__ ebias, float* __restrict__ vbias) {
    const int t = threadIdx.x;
    if (t >= 64) return;
    if (blockIdx.x == 0) {
        float acc = eb1[t];
        for (int k = 0; k < 32; ++k) acc = fmaf(state[k], ew1[(96 + k) * 64 + t], acc);
        ebias[t] = acc;
    } else {
        float acc = vb1[t];
        for (int k = 0; k < 32; ++k) acc = fmaf(state[k], vw1[(64 + k) * 64 + t], acc);
        vbias[t] = acc;
    }
}

// ---------------- prep: atoms -> bf16 ----------------

__global__ __launch_bounds__(256) void aprep_kernel(const float* __restrict__ atoms,
                                                    unsigned short* __restrict__ abf,
                                                    int nel8) {
    const int i = blockIdx.x * 256 + threadIdx.x;
    if (i >= nel8) return;
    const float* p = atoms + (size_t)i * 8;
    uint4 v;
    v.x = pk2(p[0], p[1]); v.y = pk2(p[2], p[3]);
    v.z = pk2(p[4], p[5]); v.w = pk2(p[6], p[7]);
    *(uint4*)(abf + (size_t)i * 8) = v;
}

// ---------------- prep: weights -> bf16 MFMA A-fragments ----------------
// value(lane,j) = W[32c + 8g + j][16t + b],  b=lane&15, g=lane>>4
__global__ __launch_bounds__(256) void wprep_kernel(
    const float* __restrict__ ew1, const float* __restrict__ ew2, const float* __restrict__ ew3,
    const float* __restrict__ vw1, const float* __restrict__ vw2, const float* __restrict__ vw3,
    unsigned short* __restrict__ wfe, unsigned short* __restrict__ wfv)
{
    const int idx = blockIdx.x * 256 + threadIdx.x;
    if (idx >= 44 * 64) return;
    const int fid = idx >> 6, lane = idx & 63;
    const int b = lane & 15, g = lane >> 4;
    const float* W; int N, t, c;
    if (fid < 12)      { W = ew1; N = 64; t = fid / 3;        c = fid % 3; }
    else if (fid < 20) { W = ew2; N = 64; t = (fid - 12) / 2; c = (fid - 12) % 2; }
    else if (fid < 24) { W = ew3; N = 32; t = (fid - 20) / 2; c = (fid - 20) % 2; }
    else if (fid < 32) { W = vw1; N = 64; t = (fid - 24) / 2; c = (fid - 24) % 2; }
    else if (fid < 40) { W = vw2; N = 64; t = (fid - 32) / 2; c = (fid - 32) % 2; }
    else               { W = vw3; N = 32; t = (fid - 40) / 2; c = (fid - 40) % 2; }
    unsigned short* dst = (fid < 24) ? (wfe + fid * 512) : (wfv + (fid - 24) * 512);
    for (int j = 0; j < 8; ++j) {
        const float w = W[(size_t)(32 * c + 8 * g + j) * N + 16 * t + b];
        dst[lane * 8 + j] = f2bf(w);
    }
}

// ---------------- phi_e: MFMA edge MLP + fused CSR fill/permute ----------------
// L1+L2 weights in LDS (20.5 KB), L3 weights in registers -> 37.6 KB LDS -> 4 blocks/CU.
// PERM: write bf16 output row directly at CSR slot (64B = 1 line, no amplification);
// else: legacy list fill.

template<bool PERM>
__global__ __launch_bounds__(EBLK, 8) void phi_e_mfma(
    const float* __restrict__ bonds, const int* __restrict__ ba1, const int* __restrict__ ba2,
    const unsigned short* __restrict__ abf,
    const unsigned short* __restrict__ wfe, const float* __restrict__ ebias,
    const float* __restrict__ eb2, const float* __restrict__ eb3,
    float* __restrict__ out, unsigned short* __restrict__ perm,
    int* __restrict__ wcur, int* __restrict__ list, int nb)
{
    __shared__ __align__(16) char lds[21248 + (EBLK / 64) * 2048];
    {
        const uint4* src = (const uint4*)wfe;          // 20 frags = 1280 uint4
        uint4* dst = (uint4*)lds;
        for (int i = threadIdx.x; i < 1280; i += EBLK) dst[i] = src[i];
        float* bd = (float*)(lds + 20480);
        const int t = threadIdx.x;
        if (t < 64)        bd[t] = ebias[t];
        else if (t < 128)  bd[t] = eb2[t - 64];
        else if (t < 160)  bd[t] = eb3[t - 128];
    }
    __syncthreads();

    const char* wl = lds;
    const float* bias_l = (const float*)(lds + 20480);
    const int tid = threadIdx.x;
    const int wid = tid >> 6, lane = tid & 63;
    const int b = lane & 15, g = lane >> 4;
    char* hb = lds + 21248 + wid * 2048;
    const uint32_t swz = (uint32_t)((b & 7) << 4);
    const uint32_t row = (uint32_t)(b * 128);
    const uint32_t loff = (uint32_t)(lane * 16);

    // L3 weights live in registers (16 VGPRs) -> frees 4KB LDS for occupancy
    int4v we3[2][2];
    #pragma unroll
    for (int t = 0; t < 2; ++t)
        #pragma unroll
        for (int c = 0; c < 2; ++c)
            we3[t][c] = *(const int4v*)(wfe + (20 + t * 2 + c) * 512 + lane * 8);

    const int ntile = (nb + 15) >> 4;
    const int stride = gridDim.x * (EBLK / 64);

    for (int m = blockIdx.x * (EBLK / 64) + wid; m < ntile; m += stride) {
        const int e0 = m << 4;
        const int er = min(e0 + b, nb - 1);
        const int i1 = ba1[er], i2 = ba2[er];

        // fused CSR slot claim: ack drains under the MLP body
        int pos = 0;
        if (lane < 16 && e0 + b < nb) {
            pos = atomicAdd(wcur + i1, 1);
            if (!PERM) __builtin_nontemporal_store(er, list + pos);
        }

        const int4v xa1 = *(const int4v*)(abf + (size_t)i1 * 32 + 8 * g);
        const int4v xa2 = *(const int4v*)(abf + (size_t)i2 * 32 + 8 * g);
        int4v xb;
        {
            const float* p = bonds + (size_t)er * 32 + 8 * g;
            const float4v u0 = __builtin_nontemporal_load((const float4v*)p);
            const float4v u1 = __builtin_nontemporal_load((const float4v*)p + 1);
            xb[0] = (int)pk2(u0.x, u0.y); xb[1] = (int)pk2(u0.z, u0.w);
            xb[2] = (int)pk2(u1.x, u1.y); xb[3] = (int)pk2(u1.z, u1.w);
        }

        float4v acc[4];
        #pragma unroll
        for (int t = 0; t < 4; ++t) acc[t] = *(const float4v*)(bias_l + 16 * t + 4 * g);
        #pragma unroll
        for (int t = 0; t < 4; ++t) {
            acc[t] = mfma_bf16(*(const int4v*)(wl + (t * 3 + 0) * 1024 + loff), xa1, acc[t]);
            acc[t] = mfma_bf16(*(const int4v*)(wl + (t * 3 + 1) * 1024 + loff), xa2, acc[t]);
            acc[t] = mfma_bf16(*(const int4v*)(wl + (t * 3 + 2) * 1024 + loff), xb,  acc[t]);
        }
        #pragma unroll
        for (int t = 0; t < 4; ++t) {
            const float s0 = selu_f(acc[t][0]), s1 = selu_f(acc[t][1]);
            const float s2 = selu_f(acc[t][2]), s3 = selu_f(acc[t][3]);
            const uint32_t q = (uint32_t)(t * 32 + g * 8);
            *(uint2*)(hb + row + (q ^ swz)) = make_uint2(pk2(s0, s1), pk2(s2, s3));
        }
        int4v xh0 = *(const int4v*)(hb + row + (((uint32_t)(g * 16)) ^ swz));
        int4v xh1 = *(const int4v*)(hb + row + (((uint32_t)(64 + g * 16)) ^ swz));

        #pragma unroll
        for (int t = 0; t < 4; ++t) acc[t] = *(const float4v*)(bias_l + 64 + 16 * t + 4 * g);
        #pragma unroll
        for (int t = 0; t < 4; ++t) {
            acc[t] = mfma_bf16(*(const int4v*)(wl + (12 + t * 2 + 0) * 1024 + loff), xh0, acc[t]);
            acc[t] = mfma_bf16(*(const int4v*)(wl + (12 + t * 2 + 1) * 1024 + loff), xh1, acc[t]);
        }
        #pragma unroll
        for (int t = 0; t < 4; ++t) {
            const float s0 = selu_f(acc[t][0]), s1 = selu_f(acc[t][1]);
            const float s2 = selu_f(acc[t][2]), s3 = selu_f(acc[t][3]);
            const uint32_t q = (uint32_t)(t * 32 + g * 8);
            *(uint2*)(hb + row + (q ^ swz)) = make_uint2(pk2(s0, s1), pk2(s2, s3));
        }
        xh0 = *(const int4v*)(hb + row + (((uint32_t)(g * 16)) ^ swz));
        xh1 = *(const int4v*)(hb + row + (((uint32_t)(64 + g * 16)) ^ swz));

        float4v acc3[2];
        acc3[0] = *(const float4v*)(bias_l + 128 + 4 * g);
        acc3[1] = *(const float4v*)(bias_l + 128 + 16 + 4 * g);
        #pragma unroll
        for (int t = 0; t < 2; ++t) {
            acc3[t] = mfma_bf16(we3[t][0], xh0, acc3[t]);
            acc3[t] = mfma_bf16(we3[t][1], xh1, acc3[t]);
        }

        if (PERM) pos = __shfl(pos, b);   // broadcast slot from the g==0 lane of this bond

        if (e0 + b < nb) {
            #pragma unroll
            for (int t = 0; t < 2; ++t) {
                const float o0 = selu_f(acc3[t][0]), o1 = selu_f(acc3[t][1]);
                const float o2 = selu_f(acc3[t][2]), o3 = selu_f(acc3[t][3]);
                float4v ov; ov.x = o0; ov.y = o1; ov.z = o2; ov.w = o3;
                if (PERM) {
                    // out is never re-read -> nt; perm row wants L2/L3 residency -> cached
                    __builtin_nontemporal_store(ov,
                        (float4v*)(out + (size_t)(e0 + b) * 32 + 16 * t + 4 * g));
                    uint2v pv; pv.x = pk2(o0, o1); pv.y = pk2(o2, o3);
                    *((uint2v*)(perm + (size_t)pos * 32) + (4 * t + g)) = pv;
                } else {
                    *(float4v*)(out + (size_t)(e0 + b) * 32 + 16 * t + 4 * g) = ov;
                }
            }
        }
    }
}

// ---------------- gather (PERM): linear bf16 rows per atom ----------------

__global__ __launch_bounds__(256) void gather_perm_kernel(
    const unsigned short* __restrict__ perm,
    const int* __restrict__ excl, const int* __restrict__ bases,
    const int* __restrict__ cnt, float* __restrict__ mean,
    float* __restrict__ bpart, int na)
{
    __shared__ float red[4][32];
    const int idx = blockIdx.x * 256 + threadIdx.x;
    const int a = idx >> 3, q = idx & 7;
    float4v s = {0.f, 0.f, 0.f, 0.f};
    int n = 0;
    if (a < na) {
        const int start = bases[a >> 10] + excl[a];
        n = cnt[a];
        float4v s1 = {0.f, 0.f, 0.f, 0.f};
        const unsigned short* base = perm + (size_t)start * 32 + q * 4;
        int j = 0;
        for (; j + 2 <= n; j += 2) {
            const uint2v v0 = *(const uint2v*)(base + (size_t)j * 32);
            const uint2v v1 = *(const uint2v*)(base + (size_t)(j + 1) * 32);
            s.x += bflo(v0.x);  s.y += bfhi(v0.x);  s.z += bflo(v0.y);  s.w += bfhi(v0.y);
            s1.x += bflo(v1.x); s1.y += bfhi(v1.x); s1.z += bflo(v1.y); s1.w += bfhi(v1.y);
        }
        if (j < n) {
            const uint2v v0 = *(const uint2v*)(base + (size_t)j * 32);
            s.x += bflo(v0.x); s.y += bfhi(v0.x); s.z += bflo(v0.y); s.w += bfhi(v0.y);
        }
        s += s1;
    }

    {
        float4v t = s;
        #pragma unroll
        for (int off = 8; off < 64; off <<= 1) {
            t.x += __shfl_xor(t.x, off); t.y += __shfl_xor(t.y, off);
            t.z += __shfl_xor(t.z, off); t.w += __shfl_xor(t.w, off);
        }
        const int wv = threadIdx.x >> 6;
        const int lane = threadIdx.x & 63;
        if (lane < 8) {
            red[wv][lane * 4 + 0] = t.x; red[wv][lane * 4 + 1] = t.y;
            red[wv][lane * 4 + 2] = t.z; red[wv][lane * 4 + 3] = t.w;
        }
        __syncthreads();
        if (threadIdx.x < 32) {
            const int f = threadIdx.x;
            bpart[(size_t)blockIdx.x * 32 + f] =
                red[0][f] + red[1][f] + red[2][f] + red[3][f];
        }
    }

    if (a < na) {
        const float inv = 1.0f / (float)n;   // n==0 -> NaN, matching reference 0/0
        *(float4v*)(mean + (size_t)a * 32 + q * 4) = s * inv;
    }
}

// ---------------- gather (fallback): list-indirect f32 rows ----------------

__global__ __launch_bounds__(256) void gather_mean_kernel(
    const float* __restrict__ bonds_new, const int* __restrict__ list,
    const int* __restrict__ excl, const int* __restrict__ bases,
    const int* __restrict__ cnt, float* __restrict__ mean,
    float* __restrict__ bpart, int na)
{
    __shared__ float red[4][32];
    const int idx = blockIdx.x * 256 + threadIdx.x;
    const int a = idx >> 3, q = idx & 7;
    float4v s = {0.f, 0.f, 0.f, 0.f};
    int n = 0;
    if (a < na) {
        const int start = bases[a >> 10] + excl[a];
        n = cnt[a];
        const int end = start + n;
        float4v s1 = {0.f, 0.f, 0.f, 0.f};
        int p = start;
        for (; p + 2 <= end; p += 2) {
            const int e0 = list[p], e1 = list[p + 1];
            s  += *(const float4v*)(bonds_new + (size_t)e0 * 32 + q * 4);
            s1 += *(const float4v*)(bonds_new + (size_t)e1 * 32 + q * 4);
        }
        for (; p < end; ++p)
            s += *(const float4v*)(bonds_new + (size_t)list[p] * 32 + q * 4);
        s += s1;
    }
    {
        float4v t = s;
        #pragma unroll
        for (int off = 8; off < 64; off <<= 1) {
            t.x += __shfl_xor(t.x, off); t.y += __shfl_xor(t.y, off);
            t.z += __shfl_xor(t.z, off); t.w += __shfl_xor(t.w, off);
        }
        const int wv = threadIdx.x >> 6;
        const int lane = threadIdx.x & 63;
        if (lane < 8) {
            red[wv][lane * 4 + 0] = t.x; red[wv][lane * 4 + 1] = t.y;
            red[wv][lane * 4 + 2] = t.z; red[wv][lane * 4 + 3] = t.w;
        }
        __syncthreads();
        if (threadIdx.x < 32) {
            const int f = threadIdx.x;
            bpart[(size_t)blockIdx.x * 32 + f] =
                red[0][f] + red[1][f] + red[2][f] + red[3][f];
        }
    }
    if (a < na) {
        const float inv = 1.0f / (float)n;
        *(float4v*)(mean + (size_t)a * 32 + q * 4) = s * inv;
    }
}

// ---------------- parallel reduce of per-block partials -> dst[32] ----------------

__global__ __launch_bounds__(1024) void part_reduce_kernel(const float* __restrict__ part,
                                                           float* __restrict__ dst, int nblk) {
    __shared__ float red[32][33];
    const int f = threadIdx.x & 31;
    const int c = threadIdx.x >> 5;
    float s = 0.0f;
    for (int i = c; i < nblk; i += 32) s += part[(size_t)i * 32 + f];
    red[c][f] = s;
    __syncthreads();
    if (threadIdx.x < 32) {
        float t = 0.0f;
        #pragma unroll
        for (int c2 = 0; c2 < 32; ++c2) t += red[c2][threadIdx.x];
        dst[threadIdx.x] = t;
    }
}

// ---------------- phi_v: MFMA atom MLP; per-block asum partials ----------------

__global__ __launch_bounds__(256) void phi_v_mfma(
    const unsigned short* __restrict__ abf, float* __restrict__ out /* mean in, atoms_new out */,
    const unsigned short* __restrict__ wfv, const float* __restrict__ vbias,
    const float* __restrict__ vb2, const float* __restrict__ vb3,
    float* __restrict__ apart, int na)
{
    __shared__ __align__(16) char lds_raw[4 * 2048];
    __shared__ float redv[4][32];
    const int tid = threadIdx.x;
    const int wid = tid >> 6, lane = tid & 63;
    const int b = lane & 15, g = lane >> 4;
    char* hb = lds_raw + wid * 2048;
    const uint32_t swz = (uint32_t)((b & 7) << 4);
    const uint32_t row = (uint32_t)(b * 128);

    int4v wv1[4][2], wv2[4][2], wv3[2][2];
    #pragma unroll
    for (int t = 0; t < 4; ++t)
        #pragma unroll
        for (int c = 0; c < 2; ++c) {
            wv1[t][c] = *(const int4v*)(wfv + (t * 2 + c) * 512 + lane * 8);
            wv2[t][c] = *(const int4v*)(wfv + (8 + t * 2 + c) * 512 + lane * 8);
        }
    #pragma unroll
    for (int t = 0; t < 2; ++t)
        #pragma unroll
        for (int c = 0; c < 2; ++c)
            wv3[t][c] = *(const int4v*)(wfv + (16 + t * 2 + c) * 512 + lane * 8);

    float ssum[8];
    #pragma unroll
    for (int i = 0; i < 8; ++i) ssum[i] = 0.0f;

    const int ntile = (na + 15) >> 4;
    const int m = blockIdx.x * 4 + wid;
    if (m < ntile) {
        const int a0 = m << 4;
        const int ar = (a0 + b < na) ? (a0 + b) : (na - 1);

        int4v xm;
        {
            const float* p = out + (size_t)ar * 32 + 8 * g;   // mean (f32)
            const float4v u0 = *(const float4v*)p, u1 = *(const float4v*)(p + 4);
            xm[0] = (int)pk2(u0.x, u0.y); xm[1] = (int)pk2(u0.z, u0.w);
            xm[2] = (int)pk2(u1.x, u1.y); xm[3] = (int)pk2(u1.z, u1.w);
        }
        const int4v xa = *(const int4v*)(abf + (size_t)ar * 32 + 8 * g);

        float4v acc[4];
        #pragma unroll
        for (int t = 0; t < 4; ++t) acc[t] = *(const float4v*)(vbias + 16 * t + 4 * g);
        #pragma unroll
        for (int t = 0; t < 4; ++t) {
            acc[t] = mfma_bf16(wv1[t][0], xm, acc[t]);
            acc[t] = mfma_bf16(wv1[t][1], xa, acc[t]);
        }
        #pragma unroll
        for (int t = 0; t < 4; ++t) {
            const float s0 = selu_f(acc[t][0]), s1 = selu_f(acc[t][1]);
            const float s2 = selu_f(acc[t][2]), s3 = selu_f(acc[t][3]);
            const uint32_t q = (uint32_t)(t * 32 + g * 8);
            *(uint2*)(hb + row + (q ^ swz)) = make_uint2(pk2(s0, s1), pk2(s2, s3));
        }
        int4v xh0 = *(const int4v*)(hb + row + (((uint32_t)(g * 16)) ^ swz));
        int4v xh1 = *(const int4v*)(hb + row + (((uint32_t)(64 + g * 16)) ^ swz));

        #pragma unroll
        for (int t = 0; t < 4; ++t) acc[t] = *(const float4v*)(vb2 + 16 * t + 4 * g);
        #pragma unroll
        for (int t = 0; t < 4; ++t) {
            acc[t] = mfma_bf16(wv2[t][0], xh0, acc[t]);
            acc[t] = mfma_bf16(wv2[t][1], xh1, acc[t]);
        }
        #pragma unroll
        for (int t = 0; t < 4; ++t) {
            const float s0 = selu_f(acc[t][0]), s1 = selu_f(acc[t][1]);
            const float s2 = selu_f(acc[t][2]), s3 = selu_f(acc[t][3]);
            const uint32_t q = (uint32_t)(t * 32 + g * 8);
            *(uint2*)(hb + row + (q ^ swz)) = make_uint2(pk2(s0, s1), pk2(s2, s3));
        }
        xh0 = *(const int4v*)(hb + row + (((uint32_t)(g * 16)) ^ swz));
        xh1 = *(const int4v*)(hb + row + (((uint32_t)(64 + g * 16)) ^ swz));

        float4v acc3[2];
        acc3[0] = *(const float4v*)(vb3 + 4 * g);
        acc3[1] = *(const float4v*)(vb3 + 16 + 4 * g);
        #pragma unroll
        for (int t = 0; t < 2; ++t) {
            acc3[t] = mfma_bf16(wv3[t][0], xh0, acc3[t]);
            acc3[t] = mfma_bf16(wv3[t][1], xh1, acc3[t]);
        }
        if (a0 + b < na) {
            #pragma unroll
            for (int t = 0; t < 2; ++t) {
                const float o0 = selu_f(acc3[t][0]), o1 = selu_f(acc3[t][1]);
                const float o2 = selu_f(acc3[t][2]), o3 = selu_f(acc3[t][3]);
                float4v ov; ov.x = o0; ov.y = o1; ov.z = o2; ov.w = o3;
                *(float4v*)(out + (size_t)(a0 + b) * 32 + 16 * t + 4 * g) = ov;
                ssum[t * 4 + 0] += o0; ssum[t * 4 + 1] += o1;
                ssum[t * 4 + 2] += o2; ssum[t * 4 + 3] += o3;
            }
        }
    }

    #pragma unroll
    for (int i = 0; i < 8; ++i) {
        float v = ssum[i];
        v += __shfl_xor(v, 1); v += __shfl_xor(v, 2);
        v += __shfl_xor(v, 4); v += __shfl_xor(v, 8);
        if (b == 0) redv[wid][16 * (i >> 2) + 4 * g + (i & 3)] = v;
    }
    __syncthreads();
    if (tid < 32)
        apart[(size_t)blockIdx.x * 32 + tid] =
            redv[0][tid] + redv[1][tid] + redv[2][tid] + redv[3][tid];
}

// ---------------- phi_u ----------------

__global__ __launch_bounds__(128) void phi_u_kernel(
    const float* __restrict__ bsum, const float* __restrict__ asum,
    const float* __restrict__ state,
    const float* __restrict__ w1, const float* __restrict__ b1,
    const float* __restrict__ w2, const float* __restrict__ b2,
    const float* __restrict__ w3, const float* __restrict__ b3,
    float* __restrict__ out, float inv_nb, float inv_na)
{
    __shared__ float x[96];
    __shared__ float hs[64];
    const int t = threadIdx.x;
    if (t < 32)       x[t] = bsum[t] * inv_nb;
    else if (t < 64)  x[t] = asum[t - 32] * inv_na;
    else if (t < 96)  x[t] = state[t - 64];
    __syncthreads();
    if (t < 64) {
        float acc = b1[t];
        for (int k = 0; k < 96; ++k) acc = fmaf(x[k], w1[k * 64 + t], acc);
        hs[t] = selu_f(acc);
    }
    __syncthreads();
    float acc2 = 0.0f;
    if (t < 64) {
        acc2 = b2[t];
        for (int k = 0; k < 64; ++k) acc2 = fmaf(hs[k], w2[k * 64 + t], acc2);
        acc2 = selu_f(acc2);
    }
    __syncthreads();
    if (t < 64) hs[t] = acc2;
    __syncthreads();
    if (t < 32) {
        float acc = b3[t];
        for (int k = 0; k < 64; ++k) acc = fmaf(hs[k], w3[k * 32 + t], acc);
        out[t] = selu_f(acc);
    }
}

extern "C" void kernel_launch(void* const* d_in, const int* in_sizes, int n_in,
                              void* d_out, int out_size, void* d_ws, size_t ws_size,
                              hipStream_t stream) {
    const float* bonds = (const float*)d_in[0];
    const int*   ba1   = (const int*)d_in[1];
    const int*   ba2   = (const int*)d_in[2];
    const float* atoms = (const float*)d_in[3];
    const float* state = (const float*)d_in[4];
    const float* ew1 = (const float*)d_in[5];  const float* eb1 = (const float*)d_in[6];
    const float* ew2 = (const float*)d_in[7];  const float* eb2 = (const float*)d_in[8];
    const float* ew3 = (const float*)d_in[9];  const float* eb3 = (const float*)d_in[10];
    const float* vw1 = (const float*)d_in[11]; const float* vb1 = (const float*)d_in[12];
    const float* vw2 = (const float*)d_in[13]; const float* vb2 = (const float*)d_in[14];
    const float* vw3 = (const float*)d_in[15]; const float* vb3 = (const float*)d_in[16];
    const float* uw1 = (const float*)d_in[17]; const float* ub1 = (const float*)d_in[18];
    const float* uw2 = (const float*)d_in[19]; const float* ub2 = (const float*)d_in[20];
    const float* uw3 = (const float*)d_in[21]; const float* ub3 = (const float*)d_in[22];

    const int nb = in_sizes[1];          // 2,000,000
    const int na = in_sizes[3] / 32;     // 100,000
    const int nscan = (na + SCAN_BLK - 1) / SCAN_BLK;
    const int ngather = ((na * 8) + 255) / 256;
    const int ntv = (na + 15) / 16;
    const int nvblk = (ntv + 3) / 4;

    float* out       = (float*)d_out;
    float* bonds_out = out;
    float* atoms_out = out + (size_t)nb * 32;
    float* state_out = atoms_out + (size_t)na * 32;

    // ---- workspace layout (256B-aligned chunks) ----
    char* ws = (char*)d_ws;
    size_t off = 0;
    auto alloc = [&](size_t bytes) { char* p = ws + off; off += (bytes + 255) & ~(size_t)255; return p; };
    int*   cnt   = (int*)alloc((size_t)na * 4);          // zeroed
    const size_t zero_bytes = off;
    float* bsum  = (float*)alloc(32 * 4);
    float* asum  = (float*)alloc(32 * 4);
    float* ebias = (float*)alloc(64 * 4);
    float* vbias = (float*)alloc(64 * 4);
    int*   excl  = (int*)alloc((size_t)na * 4);
    int*   bsums = (int*)alloc(128 * 4);
    int*   bases = (int*)alloc(128 * 4);
    int*   wcur  = (int*)alloc((size_t)na * 4);
    int*   list  = (int*)alloc((size_t)nb * 4);
    float* bpart = (float*)alloc((size_t)ngather * 32 * 4);
    float* apart = (float*)alloc((size_t)nvblk * 32 * 4);
    unsigned short* wfe = (unsigned short*)alloc(24 * 512 * 2);
    unsigned short* wfv = (unsigned short*)alloc(20 * 512 * 2);
    unsigned short* abf = (unsigned short*)alloc((size_t)na * 32 * 2);
    const size_t perm_bytes = (size_t)nb * 32 * 2;       // 128 MB bf16 CSR-permuted rows
    const bool use_perm = (off + perm_bytes) <= ws_size;
    unsigned short* perm = use_perm ? (unsigned short*)alloc(perm_bytes) : (unsigned short*)list;

    (void)hipMemsetAsync(d_ws, 0, zero_bytes, stream);

    bias_prep_kernel<<<2, 64, 0, stream>>>(state, ew1, eb1, vw1, vb1, ebias, vbias);
    wprep_kernel<<<(44 * 64 + 255) / 256, 256, 0, stream>>>(ew1, ew2, ew3, vw1, vw2, vw3,
                                                            wfe, wfv);
    aprep_kernel<<<(na * 4 + 255) / 256, 256, 0, stream>>>(atoms, abf, na * 4);

    cnt_kernel<<<2048, 256, 0, stream>>>(ba1, cnt, nb);
    scan_block_kernel<<<nscan, SCAN_BLK, 0, stream>>>(cnt, excl, bsums, na);
    scan_tops_kernel<<<1, 64, 0, stream>>>(bsums, bases, nscan);
    wcur_init_kernel<<<(na + 255) / 256, 256, 0, stream>>>(excl, bases, wcur, na);

    if (use_perm) {
        phi_e_mfma<true><<<1024, EBLK, 0, stream>>>(bonds, ba1, ba2, abf, wfe, ebias, eb2, eb3,
                                                    bonds_out, perm, wcur, list, nb);
        gather_perm_kernel<<<ngather, 256, 0, stream>>>(perm, excl, bases, cnt,
                                                        atoms_out, bpart, na);
    } else {
        phi_e_mfma<false><<<1024, EBLK, 0, stream>>>(bonds, ba1, ba2, abf, wfe, ebias, eb2, eb3,
                                                     bonds_out, perm, wcur, list, nb);
        gather_mean_kernel<<<ngather, 256, 0, stream>>>(bonds_out, list, excl, bases, cnt,
                                                        atoms_out, bpart, na);
    }
    part_reduce_kernel<<<1, 1024, 0, stream>>>(bpart, bsum, ngather);

    phi_v_mfma<<<nvblk, 256, 0, stream>>>(abf, atoms_out, wfv, vbias, vb2, vb3,
                                          apart, na);
    part_reduce_kernel<<<1, 1024, 0, stream>>>(apart, asum, nvblk);

    phi_u_kernel<<<1, 128, 0, stream>>>(bsum, asum, state,
                                        uw1, ub1, uw2, ub2, uw3, ub3,
                                        state_out, 1.0f / (float)nb, 1.0f / (float)na);
}

// Round 14
// 470.583 us; speedup vs baseline: 1.0213x; 1.0213x over previous
//
#include <hip/hip_runtime.h>
#include <math.h>

typedef __attribute__((ext_vector_type(4))) int    int4v;
typedef __attribute__((ext_vector_type(4))) float  float4v;
typedef __attribute__((ext_vector_type(8))) __bf16 bf16x8;

#define SCAN_BLK 1024
#define EBLK 512

static constexpr float SELU_SCALE = 1.0507009873554805f;
static constexpr float SELU_ALPHA = 1.6732632423543772f;

__device__ __forceinline__ float selu_f(float x) {
    const float sa = SELU_SCALE * SELU_ALPHA;
    float e = __expf(x);
    return x > 0.0f ? SELU_SCALE * x : fmaf(sa, e, -sa);
}

// scalar RNE f32->bf16 (cold paths: wprep only)
__device__ __forceinline__ unsigned short f2bf(float f) {
    uint32_t u = __builtin_bit_cast(uint32_t, f);
    return (unsigned short)((u + 0x7FFFu + ((u >> 16) & 1u)) >> 16);
}

// HW packed convert: a -> bits[15:0], b -> bits[31:16], RNE.
__device__ __forceinline__ uint32_t pk2(float a, float b) {
    uint32_t r;
    asm("v_cvt_pk_bf16_f32 %0, %1, %2" : "=v"(r) : "v"(a), "v"(b));
    return r;
}

__device__ __forceinline__ float4v mfma_bf16(int4v a, int4v b, float4v c) {
    return __builtin_amdgcn_mfma_f32_16x16x32_bf16(
        __builtin_bit_cast(bf16x8, a), __builtin_bit_cast(bf16x8, b), c, 0, 0, 0);
}

// ---------------- CSR build (count + scan; fill fused into phi_e) -------------

__global__ __launch_bounds__(256) void cnt_kernel(const int* __restrict__ ba1,
                                                  int* __restrict__ cnt, int nb) {
    for (int e = blockIdx.x * 256 + threadIdx.x; e < nb; e += gridDim.x * 256)
        atomicAdd(cnt + ba1[e], 1);
}

__global__ __launch_bounds__(SCAN_BLK) void scan_block_kernel(const int* __restrict__ cnt,
                                                              int* __restrict__ excl,
                                                              int* __restrict__ bsums, int na) {
    __shared__ int tmp[SCAN_BLK];
    const int t = threadIdx.x;
    const int base = blockIdx.x * SCAN_BLK;
    const int v = (base + t < na) ? cnt[base + t] : 0;
    tmp[t] = v;
    __syncthreads();
    for (int off = 1; off < SCAN_BLK; off <<= 1) {
        const int add = (t >= off) ? tmp[t - off] : 0;
        __syncthreads();
        tmp[t] += add;
        __syncthreads();
    }
    if (base + t < na) excl[base + t] = tmp[t] - v;
    if (t == SCAN_BLK - 1) bsums[blockIdx.x] = tmp[t];
}

__global__ void scan_tops_kernel(const int* __restrict__ bsums, int* __restrict__ bases,
                                 int nblocks) {
    if (threadIdx.x == 0 && blockIdx.x == 0) {
        int s = 0;
        for (int bk = 0; bk < nblocks; ++bk) { bases[bk] = s; s += bsums[bk]; }
    }
}

__global__ __launch_bounds__(256) void wcur_init_kernel(const int* __restrict__ excl,
                                                        const int* __restrict__ bases,
                                                        int* __restrict__ wcur, int na) {
    const int a = blockIdx.x * 256 + threadIdx.x;
    if (a < na) wcur[a] = bases[a >> 10] + excl[a];
}

// ---------------- prep: fold state into layer-1 bias ----------------

__global__ void bias_prep_kernel(const float* __restrict__ state,
                                 const float* __restrict__ ew1, const float* __restrict__ eb1,
                                 const float* __restrict__ vw1, const float* __restrict__ vb1,
                                 float* __restrict__ ebias, float* __restrict__ vbias) {
    const int t = threadIdx.x;
    if (t >= 64) return;
    if (blockIdx.x == 0) {
        float acc = eb1[t];
        for (int k = 0; k < 32; ++k) acc = fmaf(state[k], ew1[(96 + k) * 64 + t], acc);
        ebias[t] = acc;
    } else {
        float acc = vb1[t];
        for (int k = 0; k < 32; ++k) acc = fmaf(state[k], vw1[(64 + k) * 64 + t], acc);
        vbias[t] = acc;
    }
}

// ---------------- prep: atoms -> bf16 ----------------

__global__ __launch_bounds__(256) void aprep_kernel(const float* __restrict__ atoms,
                                                    unsigned short* __restrict__ abf,
                                                    int nel8) {
    const int i = blockIdx.x * 256 + threadIdx.x;
    if (i >= nel8) return;
    const float* p = atoms + (size_t)i * 8;
    uint4 v;
    v.x = pk2(p[0], p[1]); v.y = pk2(p[2], p[3]);
    v.z = pk2(p[4], p[5]); v.w = pk2(p[6], p[7]);
    *(uint4*)(abf + (size_t)i * 8) = v;
}

// ---------------- prep: weights -> bf16 MFMA A-fragments ----------------
// value(lane,j) = W[32c + 8g + j][16t + b],  b=lane&15, g=lane>>4
__global__ __launch_bounds__(256) void wprep_kernel(
    const float* __restrict__ ew1, const float* __restrict__ ew2, const float* __restrict__ ew3,
    const float* __restrict__ vw1, const float* __restrict__ vw2, const float* __restrict__ vw3,
    unsigned short* __restrict__ wfe, unsigned short* __restrict__ wfv)
{
    const int idx = blockIdx.x * 256 + threadIdx.x;
    if (idx >= 44 * 64) return;
    const int fid = idx >> 6, lane = idx & 63;
    const int b = lane & 15, g = lane >> 4;
    const float* W; int N, t, c;
    if (fid < 12)      { W = ew1; N = 64; t = fid / 3;        c = fid % 3; }
    else if (fid < 20) { W = ew2; N = 64; t = (fid - 12) / 2; c = (fid - 12) % 2; }
    else if (fid < 24) { W = ew3; N = 32; t = (fid - 20) / 2; c = (fid - 20) % 2; }
    else if (fid < 32) { W = vw1; N = 64; t = (fid - 24) / 2; c = (fid - 24) % 2; }
    else if (fid < 40) { W = vw2; N = 64; t = (fid - 32) / 2; c = (fid - 32) % 2; }
    else               { W = vw3; N = 32; t = (fid - 40) / 2; c = (fid - 40) % 2; }
    unsigned short* dst = (fid < 24) ? (wfe + fid * 512) : (wfv + (fid - 24) * 512);
    for (int j = 0; j < 8; ++j) {
        const float w = W[(size_t)(32 * c + 8 * g + j) * N + 16 * t + b];
        dst[lane * 8 + j] = f2bf(w);
    }
}

// ---------------- phi_e: MFMA edge MLP + fused CSR fill ----------------
// L1+L2 weights in LDS (20.5 KB), L3 weights in registers -> 37.9 KB LDS -> 4 blocks/CU.

__global__ __launch_bounds__(EBLK, 8) void phi_e_mfma(
    const float* __restrict__ bonds, const int* __restrict__ ba1, const int* __restrict__ ba2,
    const unsigned short* __restrict__ abf,
    const unsigned short* __restrict__ wfe, const float* __restrict__ ebias,
    const float* __restrict__ eb2, const float* __restrict__ eb3,
    float* __restrict__ out, int* __restrict__ wcur, int* __restrict__ list, int nb)
{
    __shared__ __align__(16) char lds[21248 + (EBLK / 64) * 2048];
    {
        const uint4* src = (const uint4*)wfe;          // 20 frags = 1280 uint4
        uint4* dst = (uint4*)lds;
        for (int i = threadIdx.x; i < 1280; i += EBLK) dst[i] = src[i];
        float* bd = (float*)(lds + 20480);
        const int t = threadIdx.x;
        if (t < 64)        bd[t] = ebias[t];
        else if (t < 128)  bd[t] = eb2[t - 64];
        else if (t < 160)  bd[t] = eb3[t - 128];
    }
    __syncthreads();

    const char* wl = lds;
    const float* bias_l = (const float*)(lds + 20480);
    const int tid = threadIdx.x;
    const int wid = tid >> 6, lane = tid & 63;
    const int b = lane & 15, g = lane >> 4;
    char* hb = lds + 21248 + wid * 2048;
    const uint32_t swz = (uint32_t)((b & 7) << 4);
    const uint32_t row = (uint32_t)(b * 128);
    const uint32_t loff = (uint32_t)(lane * 16);

    // L3 weights in registers (16 VGPRs) -> frees 4KB LDS for occupancy
    int4v we3[2][2];
    #pragma unroll
    for (int t = 0; t < 2; ++t)
        #pragma unroll
        for (int c = 0; c < 2; ++c)
            we3[t][c] = *(const int4v*)(wfe + (20 + t * 2 + c) * 512 + lane * 8);

    const int ntile = (nb + 15) >> 4;
    const int stride = gridDim.x * (EBLK / 64);

    for (int m = blockIdx.x * (EBLK / 64) + wid; m < ntile; m += stride) {
        const int e0 = m << 4;
        const int er = min(e0 + b, nb - 1);
        const int i1 = ba1[er], i2 = ba2[er];

        // fused CSR fill: ack drains under the MLP body
        if (lane < 16 && e0 + b < nb) {
            const int pos = atomicAdd(wcur + i1, 1);
            __builtin_nontemporal_store(er, list + pos);
        }

        const int4v xa1 = *(const int4v*)(abf + (size_t)i1 * 32 + 8 * g);
        const int4v xa2 = *(const int4v*)(abf + (size_t)i2 * 32 + 8 * g);
        int4v xb;
        {
            const float* p = bonds + (size_t)er * 32 + 8 * g;
            const float4v u0 = __builtin_nontemporal_load((const float4v*)p);
            const float4v u1 = __builtin_nontemporal_load((const float4v*)p + 1);
            xb[0] = (int)pk2(u0.x, u0.y); xb[1] = (int)pk2(u0.z, u0.w);
            xb[2] = (int)pk2(u1.x, u1.y); xb[3] = (int)pk2(u1.z, u1.w);
        }

        float4v acc[4];
        #pragma unroll
        for (int t = 0; t < 4; ++t) acc[t] = *(const float4v*)(bias_l + 16 * t + 4 * g);
        #pragma unroll
        for (int t = 0; t < 4; ++t) {
            acc[t] = mfma_bf16(*(const int4v*)(wl + (t * 3 + 0) * 1024 + loff), xa1, acc[t]);
            acc[t] = mfma_bf16(*(const int4v*)(wl + (t * 3 + 1) * 1024 + loff), xa2, acc[t]);
            acc[t] = mfma_bf16(*(const int4v*)(wl + (t * 3 + 2) * 1024 + loff), xb,  acc[t]);
        }
        #pragma unroll
        for (int t = 0; t < 4; ++t) {
            const float s0 = selu_f(acc[t][0]), s1 = selu_f(acc[t][1]);
            const float s2 = selu_f(acc[t][2]), s3 = selu_f(acc[t][3]);
            const uint32_t q = (uint32_t)(t * 32 + g * 8);
            *(uint2*)(hb + row + (q ^ swz)) = make_uint2(pk2(s0, s1), pk2(s2, s3));
        }
        int4v xh0 = *(const int4v*)(hb + row + (((uint32_t)(g * 16)) ^ swz));
        int4v xh1 = *(const int4v*)(hb + row + (((uint32_t)(64 + g * 16)) ^ swz));

        #pragma unroll
        for (int t = 0; t < 4; ++t) acc[t] = *(const float4v*)(bias_l + 64 + 16 * t + 4 * g);
        #pragma unroll
        for (int t = 0; t < 4; ++t) {
            acc[t] = mfma_bf16(*(const int4v*)(wl + (12 + t * 2 + 0) * 1024 + loff), xh0, acc[t]);
            acc[t] = mfma_bf16(*(const int4v*)(wl + (12 + t * 2 + 1) * 1024 + loff), xh1, acc[t]);
        }
        #pragma unroll
        for (int t = 0; t < 4; ++t) {
            const float s0 = selu_f(acc[t][0]), s1 = selu_f(acc[t][1]);
            const float s2 = selu_f(acc[t][2]), s3 = selu_f(acc[t][3]);
            const uint32_t q = (uint32_t)(t * 32 + g * 8);
            *(uint2*)(hb + row + (q ^ swz)) = make_uint2(pk2(s0, s1), pk2(s2, s3));
        }
        xh0 = *(const int4v*)(hb + row + (((uint32_t)(g * 16)) ^ swz));
        xh1 = *(const int4v*)(hb + row + (((uint32_t)(64 + g * 16)) ^ swz));

        float4v acc3[2];
        acc3[0] = *(const float4v*)(bias_l + 128 + 4 * g);
        acc3[1] = *(const float4v*)(bias_l + 128 + 16 + 4 * g);
        #pragma unroll
        for (int t = 0; t < 2; ++t) {
            acc3[t] = mfma_bf16(we3[t][0], xh0, acc3[t]);
            acc3[t] = mfma_bf16(we3[t][1], xh1, acc3[t]);
        }
        if (e0 + b < nb) {
            #pragma unroll
            for (int t = 0; t < 2; ++t) {
                float4v ov;
                ov.x = selu_f(acc3[t][0]); ov.y = selu_f(acc3[t][1]);
                ov.z = selu_f(acc3[t][2]); ov.w = selu_f(acc3[t][3]);
                // cached store: gather re-reads bonds_new soon -> keep L2/L3-resident
                *(float4v*)(out + (size_t)(e0 + b) * 32 + 16 * t + 4 * g) = ov;
            }
        }
    }
}

// ---------------- gather: per-atom mean + per-block bond-sum partials (no atomics) ----

__global__ __launch_bounds__(256) void gather_mean_kernel(
    const float* __restrict__ bonds_new, const int* __restrict__ list,
    const int* __restrict__ excl, const int* __restrict__ bases,
    const int* __restrict__ cnt, float* __restrict__ mean,
    float* __restrict__ bpart, int na)
{
    __shared__ float red[4][32];
    const int idx = blockIdx.x * 256 + threadIdx.x;
    const int a = idx >> 3, q = idx & 7;
    float4v s = {0.f, 0.f, 0.f, 0.f};
    int n = 0;
    if (a < na) {
        const int start = bases[a >> 10] + excl[a];
        n = cnt[a];
        const int end = start + n;
        float4v s1 = {0.f, 0.f, 0.f, 0.f};
        float4v s2 = {0.f, 0.f, 0.f, 0.f};
        float4v s3 = {0.f, 0.f, 0.f, 0.f};
        int p = start;
        for (; p + 4 <= end; p += 4) {
            const int e0 = list[p], e1 = list[p + 1], e2 = list[p + 2], e3 = list[p + 3];
            s  += *(const float4v*)(bonds_new + (size_t)e0 * 32 + q * 4);
            s1 += *(const float4v*)(bonds_new + (size_t)e1 * 32 + q * 4);
            s2 += *(const float4v*)(bonds_new + (size_t)e2 * 32 + q * 4);
            s3 += *(const float4v*)(bonds_new + (size_t)e3 * 32 + q * 4);
        }
        for (; p < end; ++p)
            s += *(const float4v*)(bonds_new + (size_t)list[p] * 32 + q * 4);
        s = (s + s1) + (s2 + s3);
    }

    {
        float4v t = s;
        #pragma unroll
        for (int off = 8; off < 64; off <<= 1) {
            t.x += __shfl_xor(t.x, off); t.y += __shfl_xor(t.y, off);
            t.z += __shfl_xor(t.z, off); t.w += __shfl_xor(t.w, off);
        }
        const int wv = threadIdx.x >> 6;
        const int lane = threadIdx.x & 63;
        if (lane < 8) {
            red[wv][lane * 4 + 0] = t.x; red[wv][lane * 4 + 1] = t.y;
            red[wv][lane * 4 + 2] = t.z; red[wv][lane * 4 + 3] = t.w;
        }
        __syncthreads();
        if (threadIdx.x < 32) {
            const int f = threadIdx.x;
            bpart[(size_t)blockIdx.x * 32 + f] =
                red[0][f] + red[1][f] + red[2][f] + red[3][f];
        }
    }

    if (a < na) {
        const float inv = 1.0f / (float)n;   // n==0 -> NaN, matching reference 0/0
        *(float4v*)(mean + (size_t)a * 32 + q * 4) = s * inv;
    }
}

// ---------------- parallel reduce of per-block partials -> dst[32] ----------------

__global__ __launch_bounds__(1024) void part_reduce_kernel(const float* __restrict__ part,
                                                           float* __restrict__ dst, int nblk) {
    __shared__ float red[32][33];
    const int f = threadIdx.x & 31;
    const int c = threadIdx.x >> 5;
    float s = 0.0f;
    for (int i = c; i < nblk; i += 32) s += part[(size_t)i * 32 + f];
    red[c][f] = s;
    __syncthreads();
    if (threadIdx.x < 32) {
        float t = 0.0f;
        #pragma unroll
        for (int c2 = 0; c2 < 32; ++c2) t += red[c2][threadIdx.x];
        dst[threadIdx.x] = t;
    }
}

// ---------------- phi_v: MFMA atom MLP; per-block asum partials ----------------

__global__ __launch_bounds__(256) void phi_v_mfma(
    const unsigned short* __restrict__ abf, float* __restrict__ out /* mean in, atoms_new out */,
    const unsigned short* __restrict__ wfv, const float* __restrict__ vbias,
    const float* __restrict__ vb2, const float* __restrict__ vb3,
    float* __restrict__ apart, int na)
{
    __shared__ __align__(16) char lds_raw[4 * 2048];
    __shared__ float redv[4][32];
    const int tid = threadIdx.x;
    const int wid = tid >> 6, lane = tid & 63;
    const int b = lane & 15, g = lane >> 4;
    char* hb = lds_raw + wid * 2048;
    const uint32_t swz = (uint32_t)((b & 7) << 4);
    const uint32_t row = (uint32_t)(b * 128);

    int4v wv1[4][2], wv2[4][2], wv3[2][2];
    #pragma unroll
    for (int t = 0; t < 4; ++t)
        #pragma unroll
        for (int c = 0; c < 2; ++c) {
            wv1[t][c] = *(const int4v*)(wfv + (t * 2 + c) * 512 + lane * 8);
            wv2[t][c] = *(const int4v*)(wfv + (8 + t * 2 + c) * 512 + lane * 8);
        }
    #pragma unroll
    for (int t = 0; t < 2; ++t)
        #pragma unroll
        for (int c = 0; c < 2; ++c)
            wv3[t][c] = *(const int4v*)(wfv + (16 + t * 2 + c) * 512 + lane * 8);

    float ssum[8];
    #pragma unroll
    for (int i = 0; i < 8; ++i) ssum[i] = 0.0f;

    const int ntile = (na + 15) >> 4;
    const int m = blockIdx.x * 4 + wid;
    if (m < ntile) {
        const int a0 = m << 4;
        const int ar = (a0 + b < na) ? (a0 + b) : (na - 1);

        int4v xm;
        {
            const float* p = out + (size_t)ar * 32 + 8 * g;   // mean (f32)
            const float4v u0 = *(const float4v*)p, u1 = *(const float4v*)(p + 4);
            xm[0] = (int)pk2(u0.x, u0.y); xm[1] = (int)pk2(u0.z, u0.w);
            xm[2] = (int)pk2(u1.x, u1.y); xm[3] = (int)pk2(u1.z, u1.w);
        }
        const int4v xa = *(const int4v*)(abf + (size_t)ar * 32 + 8 * g);

        float4v acc[4];
        #pragma unroll
        for (int t = 0; t < 4; ++t) acc[t] = *(const float4v*)(vbias + 16 * t + 4 * g);
        #pragma unroll
        for (int t = 0; t < 4; ++t) {
            acc[t] = mfma_bf16(wv1[t][0], xm, acc[t]);
            acc[t] = mfma_bf16(wv1[t][1], xa, acc[t]);
        }
        #pragma unroll
        for (int t = 0; t < 4; ++t) {
            const float s0 = selu_f(acc[t][0]), s1 = selu_f(acc[t][1]);
            const float s2 = selu_f(acc[t][2]), s3 = selu_f(acc[t][3]);
            const uint32_t q = (uint32_t)(t * 32 + g * 8);
            *(uint2*)(hb + row + (q ^ swz)) = make_uint2(pk2(s0, s1), pk2(s2, s3));
        }
        int4v xh0 = *(const int4v*)(hb + row + (((uint32_t)(g * 16)) ^ swz));
        int4v xh1 = *(const int4v*)(hb + row + (((uint32_t)(64 + g * 16)) ^ swz));

        #pragma unroll
        for (int t = 0; t < 4; ++t) acc[t] = *(const float4v*)(vb2 + 16 * t + 4 * g);
        #pragma unroll
        for (int t = 0; t < 4; ++t) {
            acc[t] = mfma_bf16(wv2[t][0], xh0, acc[t]);
            acc[t] = mfma_bf16(wv2[t][1], xh1, acc[t]);
        }
        #pragma unroll
        for (int t = 0; t < 4; ++t) {
            const float s0 = selu_f(acc[t][0]), s1 = selu_f(acc[t][1]);
            const float s2 = selu_f(acc[t][2]), s3 = selu_f(acc[t][3]);
            const uint32_t q = (uint32_t)(t * 32 + g * 8);
            *(uint2*)(hb + row + (q ^ swz)) = make_uint2(pk2(s0, s1), pk2(s2, s3));
        }
        xh0 = *(const int4v*)(hb + row + (((uint32_t)(g * 16)) ^ swz));
        xh1 = *(const int4v*)(hb + row + (((uint32_t)(64 + g * 16)) ^ swz));

        float4v acc3[2];
        acc3[0] = *(const float4v*)(vb3 + 4 * g);
        acc3[1] = *(const float4v*)(vb3 + 16 + 4 * g);
        #pragma unroll
        for (int t = 0; t < 2; ++t) {
            acc3[t] = mfma_bf16(wv3[t][0], xh0, acc3[t]);
            acc3[t] = mfma_bf16(wv3[t][1], xh1, acc3[t]);
        }
        if (a0 + b < na) {
            #pragma unroll
            for (int t = 0; t < 2; ++t) {
                const float o0 = selu_f(acc3[t][0]), o1 = selu_f(acc3[t][1]);
                const float o2 = selu_f(acc3[t][2]), o3 = selu_f(acc3[t][3]);
                float4v ov; ov.x = o0; ov.y = o1; ov.z = o2; ov.w = o3;
                *(float4v*)(out + (size_t)(a0 + b) * 32 + 16 * t + 4 * g) = ov;
                ssum[t * 4 + 0] += o0; ssum[t * 4 + 1] += o1;
                ssum[t * 4 + 2] += o2; ssum[t * 4 + 3] += o3;
            }
        }
    }

    #pragma unroll
    for (int i = 0; i < 8; ++i) {
        float v = ssum[i];
        v += __shfl_xor(v, 1); v += __shfl_xor(v, 2);
        v += __shfl_xor(v, 4); v += __shfl_xor(v, 8);
        if (b == 0) redv[wid][16 * (i >> 2) + 4 * g + (i & 3)] = v;
    }
    __syncthreads();
    if (tid < 32)
        apart[(size_t)blockIdx.x * 32 + tid] =
            redv[0][tid] + redv[1][tid] + redv[2][tid] + redv[3][tid];
}

// ---------------- phi_u ----------------

__global__ __launch_bounds__(128) void phi_u_kernel(
    const float* __restrict__ bsum, const float* __restrict__ asum,
    const float* __restrict__ state,
    const float* __restrict__ w1, const float* __restrict__ b1,
    const float* __restrict__ w2, const float* __restrict__ b2,
    const float* __restrict__ w3, const float* __restrict__ b3,
    float* __restrict__ out, float inv_nb, float inv_na)
{
    __shared__ float x[96];
    __shared__ float hs[64];
    const int t = threadIdx.x;
    if (t < 32)       x[t] = bsum[t] * inv_nb;
    else if (t < 64)  x[t] = asum[t - 32] * inv_na;
    else if (t < 96)  x[t] = state[t - 64];
    __syncthreads();
    if (t < 64) {
        float acc = b1[t];
        for (int k = 0; k < 96; ++k) acc = fmaf(x[k], w1[k * 64 + t], acc);
        hs[t] = selu_f(acc);
    }
    __syncthreads();
    float acc2 = 0.0f;
    if (t < 64) {
        acc2 = b2[t];
        for (int k = 0; k < 64; ++k) acc2 = fmaf(hs[k], w2[k * 64 + t], acc2);
        acc2 = selu_f(acc2);
    }
    __syncthreads();
    if (t < 64) hs[t] = acc2;
    __syncthreads();
    if (t < 32) {
        float acc = b3[t];
        for (int k = 0; k < 64; ++k) acc = fmaf(hs[k], w3[k * 32 + t], acc);
        out[t] = selu_f(acc);
    }
}

extern "C" void kernel_launch(void* const* d_in, const int* in_sizes, int n_in,
                              void* d_out, int out_size, void* d_ws, size_t ws_size,
                              hipStream_t stream) {
    const float* bonds = (const float*)d_in[0];
    const int*   ba1   = (const int*)d_in[1];
    const int*   ba2   = (const int*)d_in[2];
    const float* atoms = (const float*)d_in[3];
    const float* state = (const float*)d_in[4];
    const float* ew1 = (const float*)d_in[5];  const float* eb1 = (const float*)d_in[6];
    const float* ew2 = (const float*)d_in[7];  const float* eb2 = (const float*)d_in[8];
    const float* ew3 = (const float*)d_in[9];  const float* eb3 = (const float*)d_in[10];
    const float* vw1 = (const float*)d_in[11]; const float* vb1 = (const float*)d_in[12];
    const float* vw2 = (const float*)d_in[13]; const float* vb2 = (const float*)d_in[14];
    const float* vw3 = (const float*)d_in[15]; const float* vb3 = (const float*)d_in[16];
    const float* uw1 = (const float*)d_in[17]; const float* ub1 = (const float*)d_in[18];
    const float* uw2 = (const float*)d_in[19]; const float* ub2 = (const float*)d_in[20];
    const float* uw3 = (const float*)d_in[21]; const float* ub3 = (const float*)d_in[22];

    const int nb = in_sizes[1];          // 2,000,000
    const int na = in_sizes[3] / 32;     // 100,000
    const int nscan = (na + SCAN_BLK - 1) / SCAN_BLK;
    const int ngather = ((na * 8) + 255) / 256;
    const int ntv = (na + 15) / 16;
    const int nvblk = (ntv + 3) / 4;

    float* out       = (float*)d_out;
    float* bonds_out = out;
    float* atoms_out = out + (size_t)nb * 32;
    float* state_out = atoms_out + (size_t)na * 32;

    // ---- workspace layout (256B-aligned chunks) ----
    char* ws = (char*)d_ws;
    size_t off = 0;
    auto alloc = [&](size_t bytes) { char* p = ws + off; off += (bytes + 255) & ~(size_t)255; return p; };
    int*   cnt   = (int*)alloc((size_t)na * 4);          // zeroed
    const size_t zero_bytes = off;
    float* bsum  = (float*)alloc(32 * 4);
    float* asum  = (float*)alloc(32 * 4);
    float* ebias = (float*)alloc(64 * 4);
    float* vbias = (float*)alloc(64 * 4);
    int*   excl  = (int*)alloc((size_t)na * 4);
    int*   bsums = (int*)alloc(128 * 4);
    int*   bases = (int*)alloc(128 * 4);
    int*   wcur  = (int*)alloc((size_t)na * 4);
    int*   list  = (int*)alloc((size_t)nb * 4);
    float* bpart = (float*)alloc((size_t)ngather * 32 * 4);
    float* apart = (float*)alloc((size_t)nvblk * 32 * 4);
    unsigned short* wfe = (unsigned short*)alloc(24 * 512 * 2);
    unsigned short* wfv = (unsigned short*)alloc(20 * 512 * 2);
    unsigned short* abf = (unsigned short*)alloc((size_t)na * 32 * 2);

    (void)hipMemsetAsync(d_ws, 0, zero_bytes, stream);

    bias_prep_kernel<<<2, 64, 0, stream>>>(state, ew1, eb1, vw1, vb1, ebias, vbias);
    wprep_kernel<<<(44 * 64 + 255) / 256, 256, 0, stream>>>(ew1, ew2, ew3, vw1, vw2, vw3,
                                                            wfe, wfv);
    aprep_kernel<<<(na * 4 + 255) / 256, 256, 0, stream>>>(atoms, abf, na * 4);

    cnt_kernel<<<2048, 256, 0, stream>>>(ba1, cnt, nb);
    scan_block_kernel<<<nscan, SCAN_BLK, 0, stream>>>(cnt, excl, bsums, na);
    scan_tops_kernel<<<1, 64, 0, stream>>>(bsums, bases, nscan);
    wcur_init_kernel<<<(na + 255) / 256, 256, 0, stream>>>(excl, bases, wcur, na);

    phi_e_mfma<<<1024, EBLK, 0, stream>>>(bonds, ba1, ba2, abf, wfe, ebias, eb2, eb3,
                                          bonds_out, wcur, list, nb);

    gather_mean_kernel<<<ngather, 256, 0, stream>>>(bonds_out, list, excl, bases, cnt,
                                                    atoms_out, bpart, na);
    part_reduce_kernel<<<1, 1024, 0, stream>>>(bpart, bsum, ngather);

    phi_v_mfma<<<nvblk, 256, 0, stream>>>(abf, atoms_out, wfv, vbias, vb2, vb3,
                                          apart, na);
    part_reduce_kernel<<<1, 1024, 0, stream>>>(apart, asum, nvblk);

    phi_u_kernel<<<1, 128, 0, stream>>>(bsum, asum, state,
                                        uw1, ub1, uw2, ub2, uw3, ub3,
                                        state_out, 1.0f / (float)nb, 1.0f / (float)na);
}

// Round 15
// 436.973 us; speedup vs baseline: 1.0999x; 1.0769x over previous
//
#include <hip/hip_runtime.h>
#include <math.h>

typedef __attribute__((ext_vector_type(4))) int    int4v;
typedef __attribute__((ext_vector_type(4))) float  float4v;
typedef __attribute__((ext_vector_type(8))) __bf16 bf16x8;

#define SCAN_BLK 1024
#define EBLK 512

static constexpr float SELU_SCALE = 1.0507009873554805f;
static constexpr float SELU_ALPHA = 1.6732632423543772f;

__device__ __forceinline__ float selu_f(float x) {
    const float sa = SELU_SCALE * SELU_ALPHA;
    float e = __expf(x);
    return x > 0.0f ? SELU_SCALE * x : fmaf(sa, e, -sa);
}

// scalar RNE f32->bf16 (cold paths: wprep only)
__device__ __forceinline__ unsigned short f2bf(float f) {
    uint32_t u = __builtin_bit_cast(uint32_t, f);
    return (unsigned short)((u + 0x7FFFu + ((u >> 16) & 1u)) >> 16);
}

// HW packed convert: a -> bits[15:0], b -> bits[31:16], RNE.
__device__ __forceinline__ uint32_t pk2(float a, float b) {
    uint32_t r;
    asm("v_cvt_pk_bf16_f32 %0, %1, %2" : "=v"(r) : "v"(a), "v"(b));
    return r;
}

__device__ __forceinline__ float4v mfma_bf16(int4v a, int4v b, float4v c) {
    return __builtin_amdgcn_mfma_f32_16x16x32_bf16(
        __builtin_bit_cast(bf16x8, a), __builtin_bit_cast(bf16x8, b), c, 0, 0, 0);
}

// ---------------- CSR build (count + scan; fill fused into phi_e) -------------

__global__ __launch_bounds__(256) void cnt_kernel(const int* __restrict__ ba1,
                                                  int* __restrict__ cnt, int nb) {
    for (int e = blockIdx.x * 256 + threadIdx.x; e < nb; e += gridDim.x * 256)
        atomicAdd(cnt + ba1[e], 1);
}

__global__ __launch_bounds__(SCAN_BLK) void scan_block_kernel(const int* __restrict__ cnt,
                                                              int* __restrict__ excl,
                                                              int* __restrict__ bsums, int na) {
    __shared__ int tmp[SCAN_BLK];
    const int t = threadIdx.x;
    const int base = blockIdx.x * SCAN_BLK;
    const int v = (base + t < na) ? cnt[base + t] : 0;
    tmp[t] = v;
    __syncthreads();
    for (int off = 1; off < SCAN_BLK; off <<= 1) {
        const int add = (t >= off) ? tmp[t - off] : 0;
        __syncthreads();
        tmp[t] += add;
        __syncthreads();
    }
    if (base + t < na) excl[base + t] = tmp[t] - v;
    if (t == SCAN_BLK - 1) bsums[blockIdx.x] = tmp[t];
}

// parallel exclusive scan over <=128 block sums (was a 1-thread serial loop ~30 us)
__global__ __launch_bounds__(128) void scan_tops_kernel(const int* __restrict__ bsums,
                                                        int* __restrict__ bases, int nblocks) {
    __shared__ int tmp[128];
    const int t = threadIdx.x;
    const int v = (t < nblocks) ? bsums[t] : 0;
    tmp[t] = v;
    __syncthreads();
    for (int off = 1; off < 128; off <<= 1) {
        const int add = (t >= off) ? tmp[t - off] : 0;
        __syncthreads();
        tmp[t] += add;
        __syncthreads();
    }
    if (t < nblocks) bases[t] = tmp[t] - v;
}

__global__ __launch_bounds__(256) void wcur_init_kernel(const int* __restrict__ excl,
                                                        const int* __restrict__ bases,
                                                        int* __restrict__ wcur, int na) {
    const int a = blockIdx.x * 256 + threadIdx.x;
    if (a < na) wcur[a] = bases[a >> 10] + excl[a];
}

// ---------------- prep: fold state into layer-1 bias ----------------

__global__ void bias_prep_kernel(const float* __restrict__ state,
                                 const float* __restrict__ ew1, const float* __restrict__ eb1,
                                 const float* __restrict__ vw1, const float* __restrict__ vb1,
                                 float* __restrict__ ebias, float* __restrict__ vbias) {
    const int t = threadIdx.x;
    if (t >= 64) return;
    if (blockIdx.x == 0) {
        float acc = eb1[t];
        for (int k = 0; k < 32; ++k) acc = fmaf(state[k], ew1[(96 + k) * 64 + t], acc);
        ebias[t] = acc;
    } else {
        float acc = vb1[t];
        for (int k = 0; k < 32; ++k) acc = fmaf(state[k], vw1[(64 + k) * 64 + t], acc);
        vbias[t] = acc;
    }
}

// ---------------- prep: atoms -> bf16 ----------------

__global__ __launch_bounds__(256) void aprep_kernel(const float* __restrict__ atoms,
                                                    unsigned short* __restrict__ abf,
                                                    int nel8) {
    const int i = blockIdx.x * 256 + threadIdx.x;
    if (i >= nel8) return;
    const float* p = atoms + (size_t)i * 8;
    uint4 v;
    v.x = pk2(p[0], p[1]); v.y = pk2(p[2], p[3]);
    v.z = pk2(p[4], p[5]); v.w = pk2(p[6], p[7]);
    *(uint4*)(abf + (size_t)i * 8) = v;
}

// ---------------- prep: weights -> bf16 MFMA A-fragments ----------------
// value(lane,j) = W[32c + 8g + j][16t + b],  b=lane&15, g=lane>>4
__global__ __launch_bounds__(256) void wprep_kernel(
    const float* __restrict__ ew1, const float* __restrict__ ew2, const float* __restrict__ ew3,
    const float* __restrict__ vw1, const float* __restrict__ vw2, const float* __restrict__ vw3,
    unsigned short* __restrict__ wfe, unsigned short* __restrict__ wfv)
{
    const int idx = blockIdx.x * 256 + threadIdx.x;
    if (idx >= 44 * 64) return;
    const int fid = idx >> 6, lane = idx & 63;
    const int b = lane & 15, g = lane >> 4;
    const float* W; int N, t, c;
    if (fid < 12)      { W = ew1; N = 64; t = fid / 3;        c = fid % 3; }
    else if (fid < 20) { W = ew2; N = 64; t = (fid - 12) / 2; c = (fid - 12) % 2; }
    else if (fid < 24) { W = ew3; N = 32; t = (fid - 20) / 2; c = (fid - 20) % 2; }
    else if (fid < 32) { W = vw1; N = 64; t = (fid - 24) / 2; c = (fid - 24) % 2; }
    else if (fid < 40) { W = vw2; N = 64; t = (fid - 32) / 2; c = (fid - 32) % 2; }
    else               { W = vw3; N = 32; t = (fid - 40) / 2; c = (fid - 40) % 2; }
    unsigned short* dst = (fid < 24) ? (wfe + fid * 512) : (wfv + (fid - 24) * 512);
    for (int j = 0; j < 8; ++j) {
        const float w = W[(size_t)(32 * c + 8 * g + j) * N + 16 * t + b];
        dst[lane * 8 + j] = f2bf(w);
    }
}

// ---------------- phi_e: MFMA edge MLP + fused CSR fill, weights in LDS --------------
// (round-12 config: full weights in LDS -- best measured phi_e)

__global__ __launch_bounds__(EBLK, 8) void phi_e_mfma(
    const float* __restrict__ bonds, const int* __restrict__ ba1, const int* __restrict__ ba2,
    const unsigned short* __restrict__ abf,
    const unsigned short* __restrict__ wfe, const float* __restrict__ ebias,
    const float* __restrict__ eb2, const float* __restrict__ eb3,
    float* __restrict__ out, int* __restrict__ wcur, int* __restrict__ list, int nb)
{
    __shared__ __align__(16) char lds[25344 + (EBLK / 64) * 2048];
    {
        const uint4* src = (const uint4*)wfe;
        uint4* dst = (uint4*)lds;
        #pragma unroll
        for (int i = 0; i < 3; ++i) dst[threadIdx.x + i * EBLK] = src[threadIdx.x + i * EBLK];
        float* bd = (float*)(lds + 24576);
        const int t = threadIdx.x;
        if (t < 64)        bd[t] = ebias[t];
        else if (t < 128)  bd[t] = eb2[t - 64];
        else if (t < 160)  bd[t] = eb3[t - 128];
    }
    __syncthreads();

    const char* wl = lds;
    const float* bias_l = (const float*)(lds + 24576);
    const int tid = threadIdx.x;
    const int wid = tid >> 6, lane = tid & 63;
    const int b = lane & 15, g = lane >> 4;
    char* hb = lds + 25344 + wid * 2048;
    const uint32_t swz = (uint32_t)((b & 7) << 4);
    const uint32_t row = (uint32_t)(b * 128);
    const uint32_t loff = (uint32_t)(lane * 16);

    const int ntile = (nb + 15) >> 4;
    const int stride = gridDim.x * (EBLK / 64);

    for (int m = blockIdx.x * (EBLK / 64) + wid; m < ntile; m += stride) {
        const int e0 = m << 4;
        const int er = min(e0 + b, nb - 1);
        const int i1 = ba1[er], i2 = ba2[er];

        // fused CSR fill: ack drains under the MLP body
        if (lane < 16 && e0 + b < nb) {
            const int pos = atomicAdd(wcur + i1, 1);
            __builtin_nontemporal_store(er, list + pos);
        }

        const int4v xa1 = *(const int4v*)(abf + (size_t)i1 * 32 + 8 * g);
        const int4v xa2 = *(const int4v*)(abf + (size_t)i2 * 32 + 8 * g);
        int4v xb;
        {
            const float* p = bonds + (size_t)er * 32 + 8 * g;
            const float4v u0 = __builtin_nontemporal_load((const float4v*)p);
            const float4v u1 = __builtin_nontemporal_load((const float4v*)p + 1);
            xb[0] = (int)pk2(u0.x, u0.y); xb[1] = (int)pk2(u0.z, u0.w);
            xb[2] = (int)pk2(u1.x, u1.y); xb[3] = (int)pk2(u1.z, u1.w);
        }

        float4v acc[4];
        #pragma unroll
        for (int t = 0; t < 4; ++t) acc[t] = *(const float4v*)(bias_l + 16 * t + 4 * g);
        #pragma unroll
        for (int t = 0; t < 4; ++t) {
            acc[t] = mfma_bf16(*(const int4v*)(wl + (t * 3 + 0) * 1024 + loff), xa1, acc[t]);
            acc[t] = mfma_bf16(*(const int4v*)(wl + (t * 3 + 1) * 1024 + loff), xa2, acc[t]);
            acc[t] = mfma_bf16(*(const int4v*)(wl + (t * 3 + 2) * 1024 + loff), xb,  acc[t]);
        }
        #pragma unroll
        for (int t = 0; t < 4; ++t) {
            const float s0 = selu_f(acc[t][0]), s1 = selu_f(acc[t][1]);
            const float s2 = selu_f(acc[t][2]), s3 = selu_f(acc[t][3]);
            const uint32_t q = (uint32_t)(t * 32 + g * 8);
            *(uint2*)(hb + row + (q ^ swz)) = make_uint2(pk2(s0, s1), pk2(s2, s3));
        }
        int4v xh0 = *(const int4v*)(hb + row + (((uint32_t)(g * 16)) ^ swz));
        int4v xh1 = *(const int4v*)(hb + row + (((uint32_t)(64 + g * 16)) ^ swz));

        #pragma unroll
        for (int t = 0; t < 4; ++t) acc[t] = *(const float4v*)(bias_l + 64 + 16 * t + 4 * g);
        #pragma unroll
        for (int t = 0; t < 4; ++t) {
            acc[t] = mfma_bf16(*(const int4v*)(wl + (12 + t * 2 + 0) * 1024 + loff), xh0, acc[t]);
            acc[t] = mfma_bf16(*(const int4v*)(wl + (12 + t * 2 + 1) * 1024 + loff), xh1, acc[t]);
        }
        #pragma unroll
        for (int t = 0; t < 4; ++t) {
            const float s0 = selu_f(acc[t][0]), s1 = selu_f(acc[t][1]);
            const float s2 = selu_f(acc[t][2]), s3 = selu_f(acc[t][3]);
            const uint32_t q = (uint32_t)(t * 32 + g * 8);
            *(uint2*)(hb + row + (q ^ swz)) = make_uint2(pk2(s0, s1), pk2(s2, s3));
        }
        xh0 = *(const int4v*)(hb + row + (((uint32_t)(g * 16)) ^ swz));
        xh1 = *(const int4v*)(hb + row + (((uint32_t)(64 + g * 16)) ^ swz));

        float4v acc3[2];
        acc3[0] = *(const float4v*)(bias_l + 128 + 4 * g);
        acc3[1] = *(const float4v*)(bias_l + 128 + 16 + 4 * g);
        #pragma unroll
        for (int t = 0; t < 2; ++t) {
            acc3[t] = mfma_bf16(*(const int4v*)(wl + (20 + t * 2 + 0) * 1024 + loff), xh0, acc3[t]);
            acc3[t] = mfma_bf16(*(const int4v*)(wl + (20 + t * 2 + 1) * 1024 + loff), xh1, acc3[t]);
        }
        if (e0 + b < nb) {
            #pragma unroll
            for (int t = 0; t < 2; ++t) {
                float4v ov;
                ov.x = selu_f(acc3[t][0]); ov.y = selu_f(acc3[t][1]);
                ov.z = selu_f(acc3[t][2]); ov.w = selu_f(acc3[t][3]);
                *(float4v*)(out + (size_t)(e0 + b) * 32 + 16 * t + 4 * g) = ov;
            }
        }
    }
}

// ---------------- gather: per-atom mean + per-block bond-sum partials (no atomics) ----
// 8 rows in flight per thread (was 4): more outstanding scattered loads.

__global__ __launch_bounds__(256) void gather_mean_kernel(
    const float* __restrict__ bonds_new, const int* __restrict__ list,
    const int* __restrict__ excl, const int* __restrict__ bases,
    const int* __restrict__ cnt, float* __restrict__ mean,
    float* __restrict__ bpart, int na)
{
    __shared__ float red[4][32];
    const int idx = blockIdx.x * 256 + threadIdx.x;
    const int a = idx >> 3, q = idx & 7;
    float4v sv[8];
    #pragma unroll
    for (int i = 0; i < 8; ++i) sv[i] = (float4v){0.f, 0.f, 0.f, 0.f};
    int n = 0;
    if (a < na) {
        const int start = bases[a >> 10] + excl[a];
        n = cnt[a];
        const int end = start + n;
        int p = start;
        for (; p + 8 <= end; p += 8) {
            int e[8];
            #pragma unroll
            for (int i = 0; i < 8; ++i) e[i] = list[p + i];
            #pragma unroll
            for (int i = 0; i < 8; ++i)
                sv[i] += *(const float4v*)(bonds_new + (size_t)e[i] * 32 + q * 4);
        }
        for (; p + 2 <= end; p += 2) {
            const int e0 = list[p], e1 = list[p + 1];
            sv[0] += *(const float4v*)(bonds_new + (size_t)e0 * 32 + q * 4);
            sv[1] += *(const float4v*)(bonds_new + (size_t)e1 * 32 + q * 4);
        }
        if (p < end)
            sv[0] += *(const float4v*)(bonds_new + (size_t)list[p] * 32 + q * 4);
    }
    float4v s = ((sv[0] + sv[1]) + (sv[2] + sv[3])) + ((sv[4] + sv[5]) + (sv[6] + sv[7]));

    {
        float4v t = s;
        #pragma unroll
        for (int off = 8; off < 64; off <<= 1) {
            t.x += __shfl_xor(t.x, off); t.y += __shfl_xor(t.y, off);
            t.z += __shfl_xor(t.z, off); t.w += __shfl_xor(t.w, off);
        }
        const int wv = threadIdx.x >> 6;
        const int lane = threadIdx.x & 63;
        if (lane < 8) {
            red[wv][lane * 4 + 0] = t.x; red[wv][lane * 4 + 1] = t.y;
            red[wv][lane * 4 + 2] = t.z; red[wv][lane * 4 + 3] = t.w;
        }
        __syncthreads();
        if (threadIdx.x < 32) {
            const int f = threadIdx.x;
            bpart[(size_t)blockIdx.x * 32 + f] =
                red[0][f] + red[1][f] + red[2][f] + red[3][f];
        }
    }

    if (a < na) {
        const float inv = 1.0f / (float)n;   // n==0 -> NaN, matching reference 0/0
        *(float4v*)(mean + (size_t)a * 32 + q * 4) = s * inv;
    }
}

// ---------------- parallel reduce of per-block partials -> dst[32] ----------------

__global__ __launch_bounds__(1024) void part_reduce_kernel(const float* __restrict__ part,
                                                           float* __restrict__ dst, int nblk) {
    __shared__ float red[32][33];
    const int f = threadIdx.x & 31;
    const int c = threadIdx.x >> 5;
    float s = 0.0f;
    for (int i = c; i < nblk; i += 32) s += part[(size_t)i * 32 + f];
    red[c][f] = s;
    __syncthreads();
    if (threadIdx.x < 32) {
        float t = 0.0f;
        #pragma unroll
        for (int c2 = 0; c2 < 32; ++c2) t += red[c2][threadIdx.x];
        dst[threadIdx.x] = t;
    }
}

// ---------------- phi_v: MFMA atom MLP; per-block asum partials ----------------

__global__ __launch_bounds__(256) void phi_v_mfma(
    const unsigned short* __restrict__ abf, float* __restrict__ out /* mean in, atoms_new out */,
    const unsigned short* __restrict__ wfv, const float* __restrict__ vbias,
    const float* __restrict__ vb2, const float* __restrict__ vb3,
    float* __restrict__ apart, int na)
{
    __shared__ __align__(16) char lds_raw[4 * 2048];
    __shared__ float redv[4][32];
    const int tid = threadIdx.x;
    const int wid = tid >> 6, lane = tid & 63;
    const int b = lane & 15, g = lane >> 4;
    char* hb = lds_raw + wid * 2048;
    const uint32_t swz = (uint32_t)((b & 7) << 4);
    const uint32_t row = (uint32_t)(b * 128);

    int4v wv1[4][2], wv2[4][2], wv3[2][2];
    #pragma unroll
    for (int t = 0; t < 4; ++t)
        #pragma unroll
        for (int c = 0; c < 2; ++c) {
            wv1[t][c] = *(const int4v*)(wfv + (t * 2 + c) * 512 + lane * 8);
            wv2[t][c] = *(const int4v*)(wfv + (8 + t * 2 + c) * 512 + lane * 8);
        }
    #pragma unroll
    for (int t = 0; t < 2; ++t)
        #pragma unroll
        for (int c = 0; c < 2; ++c)
            wv3[t][c] = *(const int4v*)(wfv + (16 + t * 2 + c) * 512 + lane * 8);

    float ssum[8];
    #pragma unroll
    for (int i = 0; i < 8; ++i) ssum[i] = 0.0f;

    const int ntile = (na + 15) >> 4;
    const int m = blockIdx.x * 4 + wid;
    if (m < ntile) {
        const int a0 = m << 4;
        const int ar = (a0 + b < na) ? (a0 + b) : (na - 1);

        int4v xm;
        {
            const float* p = out + (size_t)ar * 32 + 8 * g;   // mean (f32)
            const float4v u0 = *(const float4v*)p, u1 = *(const float4v*)(p + 4);
            xm[0] = (int)pk2(u0.x, u0.y); xm[1] = (int)pk2(u0.z, u0.w);
            xm[2] = (int)pk2(u1.x, u1.y); xm[3] = (int)pk2(u1.z, u1.w);
        }
        const int4v xa = *(const int4v*)(abf + (size_t)ar * 32 + 8 * g);

        float4v acc[4];
        #pragma unroll
        for (int t = 0; t < 4; ++t) acc[t] = *(const float4v*)(vbias + 16 * t + 4 * g);
        #pragma unroll
        for (int t = 0; t < 4; ++t) {
            acc[t] = mfma_bf16(wv1[t][0], xm, acc[t]);
            acc[t] = mfma_bf16(wv1[t][1], xa, acc[t]);
        }
        #pragma unroll
        for (int t = 0; t < 4; ++t) {
            const float s0 = selu_f(acc[t][0]), s1 = selu_f(acc[t][1]);
            const float s2 = selu_f(acc[t][2]), s3 = selu_f(acc[t][3]);
            const uint32_t q = (uint32_t)(t * 32 + g * 8);
            *(uint2*)(hb + row + (q ^ swz)) = make_uint2(pk2(s0, s1), pk2(s2, s3));
        }
        int4v xh0 = *(const int4v*)(hb + row + (((uint32_t)(g * 16)) ^ swz));
        int4v xh1 = *(const int4v*)(hb + row + (((uint32_t)(64 + g * 16)) ^ swz));

        #pragma unroll
        for (int t = 0; t < 4; ++t) acc[t] = *(const float4v*)(vb2 + 16 * t + 4 * g);
        #pragma unroll
        for (int t = 0; t < 4; ++t) {
            acc[t] = mfma_bf16(wv2[t][0], xh0, acc[t]);
            acc[t] = mfma_bf16(wv2[t][1], xh1, acc[t]);
        }
        #pragma unroll
        for (int t = 0; t < 4; ++t) {
            const float s0 = selu_f(acc[t][0]), s1 = selu_f(acc[t][1]);
            const float s2 = selu_f(acc[t][2]), s3 = selu_f(acc[t][3]);
            const uint32_t q = (uint32_t)(t * 32 + g * 8);
            *(uint2*)(hb + row + (q ^ swz)) = make_uint2(pk2(s0, s1), pk2(s2, s3));
        }
        xh0 = *(const int4v*)(hb + row + (((uint32_t)(g * 16)) ^ swz));
        xh1 = *(const int4v*)(hb + row + (((uint32_t)(64 + g * 16)) ^ swz));

        float4v acc3[2];
        acc3[0] = *(const float4v*)(vb3 + 4 * g);
        acc3[1] = *(const float4v*)(vb3 + 16 + 4 * g);
        #pragma unroll
        for (int t = 0; t < 2; ++t) {
            acc3[t] = mfma_bf16(wv3[t][0], xh0, acc3[t]);
            acc3[t] = mfma_bf16(wv3[t][1], xh1, acc3[t]);
        }
        if (a0 + b < na) {
            #pragma unroll
            for (int t = 0; t < 2; ++t) {
                const float o0 = selu_f(acc3[t][0]), o1 = selu_f(acc3[t][1]);
                const float o2 = selu_f(acc3[t][2]), o3 = selu_f(acc3[t][3]);
                float4v ov; ov.x = o0; ov.y = o1; ov.z = o2; ov.w = o3;
                *(float4v*)(out + (size_t)(a0 + b) * 32 + 16 * t + 4 * g) = ov;
                ssum[t * 4 + 0] += o0; ssum[t * 4 + 1] += o1;
                ssum[t * 4 + 2] += o2; ssum[t * 4 + 3] += o3;
            }
        }
    }

    #pragma unroll
    for (int i = 0; i < 8; ++i) {
        float v = ssum[i];
        v += __shfl_xor(v, 1); v += __shfl_xor(v, 2);
        v += __shfl_xor(v, 4); v += __shfl_xor(v, 8);
        if (b == 0) redv[wid][16 * (i >> 2) + 4 * g + (i & 3)] = v;
    }
    __syncthreads();
    if (tid < 32)
        apart[(size_t)blockIdx.x * 32 + tid] =
            redv[0][tid] + redv[1][tid] + redv[2][tid] + redv[3][tid];
}

// ---------------- phi_u ----------------

__global__ __launch_bounds__(128) void phi_u_kernel(
    const float* __restrict__ bsum, const float* __restrict__ asum,
    const float* __restrict__ state,
    const float* __restrict__ w1, const float* __restrict__ b1,
    const float* __restrict__ w2, const float* __restrict__ b2,
    const float* __restrict__ w3, const float* __restrict__ b3,
    float* __restrict__ out, float inv_nb, float inv_na)
{
    __shared__ float x[96];
    __shared__ float hs[64];
    const int t = threadIdx.x;
    if (t < 32)       x[t] = bsum[t] * inv_nb;
    else if (t < 64)  x[t] = asum[t - 32] * inv_na;
    else if (t < 96)  x[t] = state[t - 64];
    __syncthreads();
    if (t < 64) {
        float acc = b1[t];
        for (int k = 0; k < 96; ++k) acc = fmaf(x[k], w1[k * 64 + t], acc);
        hs[t] = selu_f(acc);
    }
    __syncthreads();
    float acc2 = 0.0f;
    if (t < 64) {
        acc2 = b2[t];
        for (int k = 0; k < 64; ++k) acc2 = fmaf(hs[k], w2[k * 64 + t], acc2);
        acc2 = selu_f(acc2);
    }
    __syncthreads();
    if (t < 64) hs[t] = acc2;
    __syncthreads();
    if (t < 32) {
        float acc = b3[t];
        for (int k = 0; k < 64; ++k) acc = fmaf(hs[k], w3[k * 32 + t], acc);
        out[t] = selu_f(acc);
    }
}

extern "C" void kernel_launch(void* const* d_in, const int* in_sizes, int n_in,
                              void* d_out, int out_size, void* d_ws, size_t ws_size,
                              hipStream_t stream) {
    const float* bonds = (const float*)d_in[0];
    const int*   ba1   = (const int*)d_in[1];
    const int*   ba2   = (const int*)d_in[2];
    const float* atoms = (const float*)d_in[3];
    const float* state = (const float*)d_in[4];
    const float* ew1 = (const float*)d_in[5];  const float* eb1 = (const float*)d_in[6];
    const float* ew2 = (const float*)d_in[7];  const float* eb2 = (const float*)d_in[8];
    const float* ew3 = (const float*)d_in[9];  const float* eb3 = (const float*)d_in[10];
    const float* vw1 = (const float*)d_in[11]; const float* vb1 = (const float*)d_in[12];
    const float* vw2 = (const float*)d_in[13]; const float* vb2 = (const float*)d_in[14];
    const float* vw3 = (const float*)d_in[15]; const float* vb3 = (const float*)d_in[16];
    const float* uw1 = (const float*)d_in[17]; const float* ub1 = (const float*)d_in[18];
    const float* uw2 = (const float*)d_in[19]; const float* ub2 = (const float*)d_in[20];
    const float* uw3 = (const float*)d_in[21]; const float* ub3 = (const float*)d_in[22];

    const int nb = in_sizes[1];          // 2,000,000
    const int na = in_sizes[3] / 32;     // 100,000
    const int nscan = (na + SCAN_BLK - 1) / SCAN_BLK;
    const int ngather = ((na * 8) + 255) / 256;
    const int ntv = (na + 15) / 16;
    const int nvblk = (ntv + 3) / 4;

    float* out       = (float*)d_out;
    float* bonds_out = out;
    float* atoms_out = out + (size_t)nb * 32;
    float* state_out = atoms_out + (size_t)na * 32;

    // ---- workspace layout (256B-aligned chunks) ----
    char* ws = (char*)d_ws;
    size_t off = 0;
    auto alloc = [&](size_t bytes) { char* p = ws + off; off += (bytes + 255) & ~(size_t)255; return p; };
    int*   cnt   = (int*)alloc((size_t)na * 4);          // zeroed
    const size_t zero_bytes = off;
    float* bsum  = (float*)alloc(32 * 4);
    float* asum  = (float*)alloc(32 * 4);
    float* ebias = (float*)alloc(64 * 4);
    float* vbias = (float*)alloc(64 * 4);
    int*   excl  = (int*)alloc((size_t)na * 4);
    int*   bsums = (int*)alloc(128 * 4);
    int*   bases = (int*)alloc(128 * 4);
    int*   wcur  = (int*)alloc((size_t)na * 4);
    int*   list  = (int*)alloc((size_t)nb * 4);
    float* bpart = (float*)alloc((size_t)ngather * 32 * 4);
    float* apart = (float*)alloc((size_t)nvblk * 32 * 4);
    unsigned short* wfe = (unsigned short*)alloc(24 * 512 * 2);
    unsigned short* wfv = (unsigned short*)alloc(20 * 512 * 2);
    unsigned short* abf = (unsigned short*)alloc((size_t)na * 32 * 2);

    (void)hipMemsetAsync(d_ws, 0, zero_bytes, stream);

    bias_prep_kernel<<<2, 64, 0, stream>>>(state, ew1, eb1, vw1, vb1, ebias, vbias);
    wprep_kernel<<<(44 * 64 + 255) / 256, 256, 0, stream>>>(ew1, ew2, ew3, vw1, vw2, vw3,
                                                            wfe, wfv);
    aprep_kernel<<<(na * 4 + 255) / 256, 256, 0, stream>>>(atoms, abf, na * 4);

    cnt_kernel<<<2048, 256, 0, stream>>>(ba1, cnt, nb);
    scan_block_kernel<<<nscan, SCAN_BLK, 0, stream>>>(cnt, excl, bsums, na);
    scan_tops_kernel<<<1, 128, 0, stream>>>(bsums, bases, nscan);
    wcur_init_kernel<<<(na + 255) / 256, 256, 0, stream>>>(excl, bases, wcur, na);

    phi_e_mfma<<<1024, EBLK, 0, stream>>>(bonds, ba1, ba2, abf, wfe, ebias, eb2, eb3,
                                          bonds_out, wcur, list, nb);

    gather_mean_kernel<<<ngather, 256, 0, stream>>>(bonds_out, list, excl, bases, cnt,
                                                    atoms_out, bpart, na);
    part_reduce_kernel<<<1, 1024, 0, stream>>>(bpart, bsum, ngather);

    phi_v_mfma<<<nvblk, 256, 0, stream>>>(abf, atoms_out, wfv, vbias, vb2, vb3,
                                          apart, na);
    part_reduce_kernel<<<1, 1024, 0, stream>>>(apart, asum, nvblk);

    phi_u_kernel<<<1, 128, 0, stream>>>(bsum, asum, state,
                                        uw1, ub1, uw2, ub2, uw3, ub3,
                                        state_out, 1.0f / (float)nb, 1.0f / (float)na);
}

// Round 16
// 430.907 us; speedup vs baseline: 1.1154x; 1.0141x over previous
//
#include <hip/hip_runtime.h>
#include <math.h>

typedef __attribute__((ext_vector_type(4))) int    int4v;
typedef __attribute__((ext_vector_type(4))) float  float4v;
typedef __attribute__((ext_vector_type(8))) __bf16 bf16x8;

#define SCAN_BLK 1024
#define EBLK 512

static constexpr float SELU_SCALE = 1.0507009873554805f;
static constexpr float SELU_ALPHA = 1.6732632423543772f;

__device__ __forceinline__ float selu_f(float x) {
    const float sa = SELU_SCALE * SELU_ALPHA;
    float e = __expf(x);
    return x > 0.0f ? SELU_SCALE * x : fmaf(sa, e, -sa);
}

__device__ __forceinline__ unsigned short f2bf(float f) {
    uint32_t u = __builtin_bit_cast(uint32_t, f);
    return (unsigned short)((u + 0x7FFFu + ((u >> 16) & 1u)) >> 16);
}

// HW packed convert: a -> bits[15:0], b -> bits[31:16], RNE.
__device__ __forceinline__ uint32_t pk2(float a, float b) {
    uint32_t r;
    asm("v_cvt_pk_bf16_f32 %0, %1, %2" : "=v"(r) : "v"(a), "v"(b));
    return r;
}

__device__ __forceinline__ float4v mfma_bf16(int4v a, int4v b, float4v c) {
    return __builtin_amdgcn_mfma_f32_16x16x32_bf16(
        __builtin_bit_cast(bf16x8, a), __builtin_bit_cast(bf16x8, b), c, 0, 0, 0);
}

// ---------------- CSR build (count + scan; fill fused into phi_e) -------------

__global__ __launch_bounds__(256) void cnt_kernel(const int* __restrict__ ba1,
                                                  int* __restrict__ cnt, int nb) {
    for (int e = blockIdx.x * 256 + threadIdx.x; e < nb; e += gridDim.x * 256)
        atomicAdd(cnt + ba1[e], 1);
}

__global__ __launch_bounds__(SCAN_BLK) void scan_block_kernel(const int* __restrict__ cnt,
                                                              int* __restrict__ excl,
                                                              int* __restrict__ bsums, int na) {
    __shared__ int tmp[SCAN_BLK];
    const int t = threadIdx.x;
    const int base = blockIdx.x * SCAN_BLK;
    const int v = (base + t < na) ? cnt[base + t] : 0;
    tmp[t] = v;
    __syncthreads();
    for (int off = 1; off < SCAN_BLK; off <<= 1) {
        const int add = (t >= off) ? tmp[t - off] : 0;
        __syncthreads();
        tmp[t] += add;
        __syncthreads();
    }
    if (base + t < na) excl[base + t] = tmp[t] - v;
    if (t == SCAN_BLK - 1) bsums[blockIdx.x] = tmp[t];
}

__global__ __launch_bounds__(128) void scan_tops_kernel(const int* __restrict__ bsums,
                                                        int* __restrict__ bases, int nblocks) {
    __shared__ int tmp[128];
    const int t = threadIdx.x;
    const int v = (t < nblocks) ? bsums[t] : 0;
    tmp[t] = v;
    __syncthreads();
    for (int off = 1; off < 128; off <<= 1) {
        const int add = (t >= off) ? tmp[t - off] : 0;
        __syncthreads();
        tmp[t] += add;
        __syncthreads();
    }
    if (t < nblocks) bases[t] = tmp[t] - v;
}

__global__ __launch_bounds__(256) void wcur_init_kernel(const int* __restrict__ excl,
                                                        const int* __restrict__ bases,
                                                        int* __restrict__ wcur, int na) {
    const int a = blockIdx.x * 256 + threadIdx.x;
    if (a < na) wcur[a] = bases[a >> 10] + excl[a];
}

// ---------------- fused prep: atoms->bf16, weight fragments, state-folded biases ------

__global__ __launch_bounds__(256) void prep_all_kernel(
    const float* __restrict__ atoms, unsigned short* __restrict__ abf, int nel8,
    const float* __restrict__ ew1, const float* __restrict__ ew2, const float* __restrict__ ew3,
    const float* __restrict__ vw1, const float* __restrict__ vw2, const float* __restrict__ vw3,
    unsigned short* __restrict__ wfe, unsigned short* __restrict__ wfv,
    const float* __restrict__ state,
    const float* __restrict__ eb1, const float* __restrict__ vb1,
    float* __restrict__ ebias, float* __restrict__ vbias)
{
    const int i = blockIdx.x * 256 + threadIdx.x;
    if (i < nel8) {
        const float* p = atoms + (size_t)i * 8;
        uint4 v;
        v.x = pk2(p[0], p[1]); v.y = pk2(p[2], p[3]);
        v.z = pk2(p[4], p[5]); v.w = pk2(p[6], p[7]);
        *(uint4*)(abf + (size_t)i * 8) = v;
    }
    if (i < 44 * 64) {
        const int fid = i >> 6, lane = i & 63;
        const int b = lane & 15, g = lane >> 4;
        const float* W; int N, t, c;
        if (fid < 12)      { W = ew1; N = 64; t = fid / 3;        c = fid % 3; }
        else if (fid < 20) { W = ew2; N = 64; t = (fid - 12) / 2; c = (fid - 12) % 2; }
        else if (fid < 24) { W = ew3; N = 32; t = (fid - 20) / 2; c = (fid - 20) % 2; }
        else if (fid < 32) { W = vw1; N = 64; t = (fid - 24) / 2; c = (fid - 24) % 2; }
        else if (fid < 40) { W = vw2; N = 64; t = (fid - 32) / 2; c = (fid - 32) % 2; }
        else               { W = vw3; N = 32; t = (fid - 40) / 2; c = (fid - 40) % 2; }
        unsigned short* dst = (fid < 24) ? (wfe + fid * 512) : (wfv + (fid - 24) * 512);
        for (int j = 0; j < 8; ++j) {
            const float w = W[(size_t)(32 * c + 8 * g + j) * N + 16 * t + b];
            dst[lane * 8 + j] = f2bf(w);
        }
    }
    if (i < 64) {
        float acc = eb1[i];
        for (int k = 0; k < 32; ++k) acc = fmaf(state[k], ew1[(96 + k) * 64 + i], acc);
        ebias[i] = acc;
    } else if (i < 128) {
        const int t = i - 64;
        float acc = vb1[t];
        for (int k = 0; k < 32; ++k) acc = fmaf(state[k], vw1[(64 + k) * 64 + t], acc);
        vbias[t] = acc;
    }
}

// ---------------- phi_e: MFMA edge MLP, unroll-2 tile pairs + fused CSR fill ----------
// Per wave: 32 bonds (2 tiles). All loads for both tiles issue at iteration top;
// tile-B operands stay raw in registers until B's compute -> latency drains under A.

__global__ __launch_bounds__(EBLK, 4) void phi_e_mfma(
    const float* __restrict__ bonds, const int* __restrict__ ba1, const int* __restrict__ ba2,
    const unsigned short* __restrict__ abf,
    const unsigned short* __restrict__ wfe, const float* __restrict__ ebias,
    const float* __restrict__ eb2, const float* __restrict__ eb3,
    float* __restrict__ out, int* __restrict__ wcur, int* __restrict__ list, int nb)
{
    __shared__ __align__(16) char lds[25344 + (EBLK / 64) * 2048];
    {
        const uint4* src = (const uint4*)wfe;
        uint4* dst = (uint4*)lds;
        #pragma unroll
        for (int i = 0; i < 3; ++i) dst[threadIdx.x + i * EBLK] = src[threadIdx.x + i * EBLK];
        float* bd = (float*)(lds + 24576);
        const int t = threadIdx.x;
        if (t < 64)        bd[t] = ebias[t];
        else if (t < 128)  bd[t] = eb2[t - 64];
        else if (t < 160)  bd[t] = eb3[t - 128];
    }
    __syncthreads();

    const char* wl = lds;
    const float* bias_l = (const float*)(lds + 24576);
    const int tid = threadIdx.x;
    const int wid = tid >> 6, lane = tid & 63;
    const int b = lane & 15, g = lane >> 4;
    char* hb = lds + 25344 + wid * 2048;
    const uint32_t swz = (uint32_t)((b & 7) << 4);
    const uint32_t row = (uint32_t)(b * 128);
    const uint32_t loff = (uint32_t)(lane * 16);

    const int ntile = (nb + 15) >> 4;
    const int npair = (ntile + 1) >> 1;
    const int stride = gridDim.x * (EBLK / 64);

    // full MLP for one 16-bond tile; inputs already packed bf16x8
    auto mlp = [&](int4v xa1, int4v xa2, int4v xb, int e0) {
        float4v acc[4];
        #pragma unroll
        for (int t = 0; t < 4; ++t) acc[t] = *(const float4v*)(bias_l + 16 * t + 4 * g);
        #pragma unroll
        for (int t = 0; t < 4; ++t) {
            acc[t] = mfma_bf16(*(const int4v*)(wl + (t * 3 + 0) * 1024 + loff), xa1, acc[t]);
            acc[t] = mfma_bf16(*(const int4v*)(wl + (t * 3 + 1) * 1024 + loff), xa2, acc[t]);
            acc[t] = mfma_bf16(*(const int4v*)(wl + (t * 3 + 2) * 1024 + loff), xb,  acc[t]);
        }
        #pragma unroll
        for (int t = 0; t < 4; ++t) {
            const float s0 = selu_f(acc[t][0]), s1 = selu_f(acc[t][1]);
            const float s2 = selu_f(acc[t][2]), s3 = selu_f(acc[t][3]);
            const uint32_t q = (uint32_t)(t * 32 + g * 8);
            *(uint2*)(hb + row + (q ^ swz)) = make_uint2(pk2(s0, s1), pk2(s2, s3));
        }
        int4v xh0 = *(const int4v*)(hb + row + (((uint32_t)(g * 16)) ^ swz));
        int4v xh1 = *(const int4v*)(hb + row + (((uint32_t)(64 + g * 16)) ^ swz));

        #pragma unroll
        for (int t = 0; t < 4; ++t) acc[t] = *(const float4v*)(bias_l + 64 + 16 * t + 4 * g);
        #pragma unroll
        for (int t = 0; t < 4; ++t) {
            acc[t] = mfma_bf16(*(const int4v*)(wl + (12 + t * 2 + 0) * 1024 + loff), xh0, acc[t]);
            acc[t] = mfma_bf16(*(const int4v*)(wl + (12 + t * 2 + 1) * 1024 + loff), xh1, acc[t]);
        }
        #pragma unroll
        for (int t = 0; t < 4; ++t) {
            const float s0 = selu_f(acc[t][0]), s1 = selu_f(acc[t][1]);
            const float s2 = selu_f(acc[t][2]), s3 = selu_f(acc[t][3]);
            const uint32_t q = (uint32_t)(t * 32 + g * 8);
            *(uint2*)(hb + row + (q ^ swz)) = make_uint2(pk2(s0, s1), pk2(s2, s3));
        }
        xh0 = *(const int4v*)(hb + row + (((uint32_t)(g * 16)) ^ swz));
        xh1 = *(const int4v*)(hb + row + (((uint32_t)(64 + g * 16)) ^ swz));

        float4v acc3[2];
        acc3[0] = *(const float4v*)(bias_l + 128 + 4 * g);
        acc3[1] = *(const float4v*)(bias_l + 128 + 16 + 4 * g);
        #pragma unroll
        for (int t = 0; t < 2; ++t) {
            acc3[t] = mfma_bf16(*(const int4v*)(wl + (20 + t * 2 + 0) * 1024 + loff), xh0, acc3[t]);
            acc3[t] = mfma_bf16(*(const int4v*)(wl + (20 + t * 2 + 1) * 1024 + loff), xh1, acc3[t]);
        }
        if (e0 + b < nb) {
            #pragma unroll
            for (int t = 0; t < 2; ++t) {
                float4v ov;
                ov.x = selu_f(acc3[t][0]); ov.y = selu_f(acc3[t][1]);
                ov.z = selu_f(acc3[t][2]); ov.w = selu_f(acc3[t][3]);
                *(float4v*)(out + (size_t)(e0 + b) * 32 + 16 * t + 4 * g) = ov;
            }
        }
    };

    for (int P = blockIdx.x * (EBLK / 64) + wid; P < npair; P += stride) {
        const int mA = P << 1;
        const bool hasB = (mA + 1) < ntile;
        const int e0a = mA << 4;
        const int e0b = e0a + 16;
        const int era = min(e0a + b, nb - 1);
        const int erb = hasB ? min(e0b + b, nb - 1) : era;
        const int i1a = ba1[era], i2a = ba2[era];
        const int i1b = ba1[erb], i2b = ba2[erb];

        // fused CSR fill for both tiles; acks drain under the MLP bodies
        if (lane < 16) {
            if (e0a + b < nb) {
                const int pos = atomicAdd(wcur + i1a, 1);
                __builtin_nontemporal_store(era, list + pos);
            }
            if (hasB && e0b + b < nb) {
                const int pos = atomicAdd(wcur + i1b, 1);
                __builtin_nontemporal_store(erb, list + pos);
            }
        }

        // issue ALL loads for both tiles now
        const int4v xa1a = *(const int4v*)(abf + (size_t)i1a * 32 + 8 * g);
        const int4v xa2a = *(const int4v*)(abf + (size_t)i2a * 32 + 8 * g);
        const float* pa = bonds + (size_t)era * 32 + 8 * g;
        const float4v ua0 = __builtin_nontemporal_load((const float4v*)pa);
        const float4v ua1 = __builtin_nontemporal_load((const float4v*)pa + 1);
        const int4v xa1b = *(const int4v*)(abf + (size_t)i1b * 32 + 8 * g);
        const int4v xa2b = *(const int4v*)(abf + (size_t)i2b * 32 + 8 * g);
        const float* pb = bonds + (size_t)erb * 32 + 8 * g;
        const float4v ub0 = __builtin_nontemporal_load((const float4v*)pb);
        const float4v ub1 = __builtin_nontemporal_load((const float4v*)pb + 1);

        // tile A: pack + compute (B's loads drain underneath)
        {
            int4v xb;
            xb[0] = (int)pk2(ua0.x, ua0.y); xb[1] = (int)pk2(ua0.z, ua0.w);
            xb[2] = (int)pk2(ua1.x, ua1.y); xb[3] = (int)pk2(ua1.z, ua1.w);
            mlp(xa1a, xa2a, xb, e0a);
        }
        // tile B
        if (hasB) {
            int4v xb;
            xb[0] = (int)pk2(ub0.x, ub0.y); xb[1] = (int)pk2(ub0.z, ub0.w);
            xb[2] = (int)pk2(ub1.x, ub1.y); xb[3] = (int)pk2(ub1.z, ub1.w);
            mlp(xa1b, xa2b, xb, e0b);
        }
    }
}

// ---------------- gather: per-atom mean + per-block bond-sum partials (no atomics) ----

__global__ __launch_bounds__(256) void gather_mean_kernel(
    const float* __restrict__ bonds_new, const int* __restrict__ list,
    const int* __restrict__ excl, const int* __restrict__ bases,
    const int* __restrict__ cnt, float* __restrict__ mean,
    float* __restrict__ bpart, int na)
{
    __shared__ float red[4][32];
    const int idx = blockIdx.x * 256 + threadIdx.x;
    const int a = idx >> 3, q = idx & 7;
    float4v sv[8];
    #pragma unroll
    for (int i = 0; i < 8; ++i) sv[i] = (float4v){0.f, 0.f, 0.f, 0.f};
    int n = 0;
    if (a < na) {
        const int start = bases[a >> 10] + excl[a];
        n = cnt[a];
        const int end = start + n;
        int p = start;
        for (; p + 8 <= end; p += 8) {
            int e[8];
            #pragma unroll
            for (int i = 0; i < 8; ++i) e[i] = list[p + i];
            #pragma unroll
            for (int i = 0; i < 8; ++i)
                sv[i] += *(const float4v*)(bonds_new + (size_t)e[i] * 32 + q * 4);
        }
        for (; p + 2 <= end; p += 2) {
            const int e0 = list[p], e1 = list[p + 1];
            sv[0] += *(const float4v*)(bonds_new + (size_t)e0 * 32 + q * 4);
            sv[1] += *(const float4v*)(bonds_new + (size_t)e1 * 32 + q * 4);
        }
        if (p < end)
            sv[0] += *(const float4v*)(bonds_new + (size_t)list[p] * 32 + q * 4);
    }
    float4v s = ((sv[0] + sv[1]) + (sv[2] + sv[3])) + ((sv[4] + sv[5]) + (sv[6] + sv[7]));

    {
        float4v t = s;
        #pragma unroll
        for (int off = 8; off < 64; off <<= 1) {
            t.x += __shfl_xor(t.x, off); t.y += __shfl_xor(t.y, off);
            t.z += __shfl_xor(t.z, off); t.w += __shfl_xor(t.w, off);
        }
        const int wv = threadIdx.x >> 6;
        const int lane = threadIdx.x & 63;
        if (lane < 8) {
            red[wv][lane * 4 + 0] = t.x; red[wv][lane * 4 + 1] = t.y;
            red[wv][lane * 4 + 2] = t.z; red[wv][lane * 4 + 3] = t.w;
        }
        __syncthreads();
        if (threadIdx.x < 32) {
            const int f = threadIdx.x;
            bpart[(size_t)blockIdx.x * 32 + f] =
                red[0][f] + red[1][f] + red[2][f] + red[3][f];
        }
    }

    if (a < na) {
        const float inv = 1.0f / (float)n;   // n==0 -> NaN, matching reference 0/0
        *(float4v*)(mean + (size_t)a * 32 + q * 4) = s * inv;
    }
}

// ---------------- parallel reduce of per-block partials -> dst[32] ----------------

__global__ __launch_bounds__(1024) void part_reduce_kernel(const float* __restrict__ part,
                                                           float* __restrict__ dst, int nblk) {
    __shared__ float red[32][33];
    const int f = threadIdx.x & 31;
    const int c = threadIdx.x >> 5;
    float s = 0.0f;
    for (int i = c; i < nblk; i += 32) s += part[(size_t)i * 32 + f];
    red[c][f] = s;
    __syncthreads();
    if (threadIdx.x < 32) {
        float t = 0.0f;
        #pragma unroll
        for (int c2 = 0; c2 < 32; ++c2) t += red[c2][threadIdx.x];
        dst[threadIdx.x] = t;
    }
}

// ---------------- phi_v: MFMA atom MLP; per-block asum partials ----------------

__global__ __launch_bounds__(256) void phi_v_mfma(
    const unsigned short* __restrict__ abf, float* __restrict__ out /* mean in, atoms_new out */,
    const unsigned short* __restrict__ wfv, const float* __restrict__ vbias,
    const float* __restrict__ vb2, const float* __restrict__ vb3,
    float* __restrict__ apart, int na)
{
    __shared__ __align__(16) char lds_raw[4 * 2048];
    __shared__ float redv[4][32];
    const int tid = threadIdx.x;
    const int wid = tid >> 6, lane = tid & 63;
    const int b = lane & 15, g = lane >> 4;
    char* hb = lds_raw + wid * 2048;
    const uint32_t swz = (uint32_t)((b & 7) << 4);
    const uint32_t row = (uint32_t)(b * 128);

    int4v wv1[4][2], wv2[4][2], wv3[2][2];
    #pragma unroll
    for (int t = 0; t < 4; ++t)
        #pragma unroll
        for (int c = 0; c < 2; ++c) {
            wv1[t][c] = *(const int4v*)(wfv + (t * 2 + c) * 512 + lane * 8);
            wv2[t][c] = *(const int4v*)(wfv + (8 + t * 2 + c) * 512 + lane * 8);
        }
    #pragma unroll
    for (int t = 0; t < 2; ++t)
        #pragma unroll
        for (int c = 0; c < 2; ++c)
            wv3[t][c] = *(const int4v*)(wfv + (16 + t * 2 + c) * 512 + lane * 8);

    float ssum[8];
    #pragma unroll
    for (int i = 0; i < 8; ++i) ssum[i] = 0.0f;

    const int ntile = (na + 15) >> 4;
    const int m = blockIdx.x * 4 + wid;
    if (m < ntile) {
        const int a0 = m << 4;
        const int ar = (a0 + b < na) ? (a0 + b) : (na - 1);

        int4v xm;
        {
            const float* p = out + (size_t)ar * 32 + 8 * g;   // mean (f32)
            const float4v u0 = *(const float4v*)p, u1 = *(const float4v*)(p + 4);
            xm[0] = (int)pk2(u0.x, u0.y); xm[1] = (int)pk2(u0.z, u0.w);
            xm[2] = (int)pk2(u1.x, u1.y); xm[3] = (int)pk2(u1.z, u1.w);
        }
        const int4v xa = *(const int4v*)(abf + (size_t)ar * 32 + 8 * g);

        float4v acc[4];
        #pragma unroll
        for (int t = 0; t < 4; ++t) acc[t] = *(const float4v*)(vbias + 16 * t + 4 * g);
        #pragma unroll
        for (int t = 0; t < 4; ++t) {
            acc[t] = mfma_bf16(wv1[t][0], xm, acc[t]);
            acc[t] = mfma_bf16(wv1[t][1], xa, acc[t]);
        }
        #pragma unroll
        for (int t = 0; t < 4; ++t) {
            const float s0 = selu_f(acc[t][0]), s1 = selu_f(acc[t][1]);
            const float s2 = selu_f(acc[t][2]), s3 = selu_f(acc[t][3]);
            const uint32_t q = (uint32_t)(t * 32 + g * 8);
            *(uint2*)(hb + row + (q ^ swz)) = make_uint2(pk2(s0, s1), pk2(s2, s3));
        }
        int4v xh0 = *(const int4v*)(hb + row + (((uint32_t)(g * 16)) ^ swz));
        int4v xh1 = *(const int4v*)(hb + row + (((uint32_t)(64 + g * 16)) ^ swz));

        #pragma unroll
        for (int t = 0; t < 4; ++t) acc[t] = *(const float4v*)(vb2 + 16 * t + 4 * g);
        #pragma unroll
        for (int t = 0; t < 4; ++t) {
            acc[t] = mfma_bf16(wv2[t][0], xh0, acc[t]);
            acc[t] = mfma_bf16(wv2[t][1], xh1, acc[t]);
        }
        #pragma unroll
        for (int t = 0; t < 4; ++t) {
            const float s0 = selu_f(acc[t][0]), s1 = selu_f(acc[t][1]);
            const float s2 = selu_f(acc[t][2]), s3 = selu_f(acc[t][3]);
            const uint32_t q = (uint32_t)(t * 32 + g * 8);
            *(uint2*)(hb + row + (q ^ swz)) = make_uint2(pk2(s0, s1), pk2(s2, s3));
        }
        xh0 = *(const int4v*)(hb + row + (((uint32_t)(g * 16)) ^ swz));
        xh1 = *(const int4v*)(hb + row + (((uint32_t)(64 + g * 16)) ^ swz));

        float4v acc3[2];
        acc3[0] = *(const float4v*)(vb3 + 4 * g);
        acc3[1] = *(const float4v*)(vb3 + 16 + 4 * g);
        #pragma unroll
        for (int t = 0; t < 2; ++t) {
            acc3[t] = mfma_bf16(wv3[t][0], xh0, acc3[t]);
            acc3[t] = mfma_bf16(wv3[t][1], xh1, acc3[t]);
        }
        if (a0 + b < na) {
            #pragma unroll
            for (int t = 0; t < 2; ++t) {
                const float o0 = selu_f(acc3[t][0]), o1 = selu_f(acc3[t][1]);
                const float o2 = selu_f(acc3[t][2]), o3 = selu_f(acc3[t][3]);
                float4v ov; ov.x = o0; ov.y = o1; ov.z = o2; ov.w = o3;
                *(float4v*)(out + (size_t)(a0 + b) * 32 + 16 * t + 4 * g) = ov;
                ssum[t * 4 + 0] += o0; ssum[t * 4 + 1] += o1;
                ssum[t * 4 + 2] += o2; ssum[t * 4 + 3] += o3;
            }
        }
    }

    #pragma unroll
    for (int i = 0; i < 8; ++i) {
        float v = ssum[i];
        v += __shfl_xor(v, 1); v += __shfl_xor(v, 2);
        v += __shfl_xor(v, 4); v += __shfl_xor(v, 8);
        if (b == 0) redv[wid][16 * (i >> 2) + 4 * g + (i & 3)] = v;
    }
    __syncthreads();
    if (tid < 32)
        apart[(size_t)blockIdx.x * 32 + tid] =
            redv[0][tid] + redv[1][tid] + redv[2][tid] + redv[3][tid];
}

// ---------------- phi_u ----------------

__global__ __launch_bounds__(128) void phi_u_kernel(
    const float* __restrict__ bsum, const float* __restrict__ asum,
    const float* __restrict__ state,
    const float* __restrict__ w1, const float* __restrict__ b1,
    const float* __restrict__ w2, const float* __restrict__ b2,
    const float* __restrict__ w3, const float* __restrict__ b3,
    float* __restrict__ out, float inv_nb, float inv_na)
{
    __shared__ float x[96];
    __shared__ float hs[64];
    const int t = threadIdx.x;
    if (t < 32)       x[t] = bsum[t] * inv_nb;
    else if (t < 64)  x[t] = asum[t - 32] * inv_na;
    else if (t < 96)  x[t] = state[t - 64];
    __syncthreads();
    if (t < 64) {
        float acc = b1[t];
        for (int k = 0; k < 96; ++k) acc = fmaf(x[k], w1[k * 64 + t], acc);
        hs[t] = selu_f(acc);
    }
    __syncthreads();
    float acc2 = 0.0f;
    if (t < 64) {
        acc2 = b2[t];
        for (int k = 0; k < 64; ++k) acc2 = fmaf(hs[k], w2[k * 64 + t], acc2);
        acc2 = selu_f(acc2);
    }
    __syncthreads();
    if (t < 64) hs[t] = acc2;
    __syncthreads();
    if (t < 32) {
        float acc = b3[t];
        for (int k = 0; k < 64; ++k) acc = fmaf(hs[k], w3[k * 32 + t], acc);
        out[t] = selu_f(acc);
    }
}

extern "C" void kernel_launch(void* const* d_in, const int* in_sizes, int n_in,
                              void* d_out, int out_size, void* d_ws, size_t ws_size,
                              hipStream_t stream) {
    const float* bonds = (const float*)d_in[0];
    const int*   ba1   = (const int*)d_in[1];
    const int*   ba2   = (const int*)d_in[2];
    const float* atoms = (const float*)d_in[3];
    const float* state = (const float*)d_in[4];
    const float* ew1 = (const float*)d_in[5];  const float* eb1 = (const float*)d_in[6];
    const float* ew2 = (const float*)d_in[7];  const float* eb2 = (const float*)d_in[8];
    const float* ew3 = (const float*)d_in[9];  const float* eb3 = (const float*)d_in[10];
    const float* vw1 = (const float*)d_in[11]; const float* vb1 = (const float*)d_in[12];
    const float* vw2 = (const float*)d_in[13]; const float* vb2 = (const float*)d_in[14];
    const float* vw3 = (const float*)d_in[15]; const float* vb3 = (const float*)d_in[16];
    const float* uw1 = (const float*)d_in[17]; const float* ub1 = (const float*)d_in[18];
    const float* uw2 = (const float*)d_in[19]; const float* ub2 = (const float*)d_in[20];
    const float* uw3 = (const float*)d_in[21]; const float* ub3 = (const float*)d_in[22];

    const int nb = in_sizes[1];          // 2,000,000
    const int na = in_sizes[3] / 32;     // 100,000
    const int nscan = (na + SCAN_BLK - 1) / SCAN_BLK;
    const int ngather = ((na * 8) + 255) / 256;
    const int ntv = (na + 15) / 16;
    const int nvblk = (ntv + 3) / 4;

    float* out       = (float*)d_out;
    float* bonds_out = out;
    float* atoms_out = out + (size_t)nb * 32;
    float* state_out = atoms_out + (size_t)na * 32;

    // ---- workspace layout (256B-aligned chunks) ----
    char* ws = (char*)d_ws;
    size_t off = 0;
    auto alloc = [&](size_t bytes) { char* p = ws + off; off += (bytes + 255) & ~(size_t)255; return p; };
    int*   cnt   = (int*)alloc((size_t)na * 4);          // zeroed
    const size_t zero_bytes = off;
    float* bsum  = (float*)alloc(32 * 4);
    float* asum  = (float*)alloc(32 * 4);
    float* ebias = (float*)alloc(64 * 4);
    float* vbias = (float*)alloc(64 * 4);
    int*   excl  = (int*)alloc((size_t)na * 4);
    int*   bsums = (int*)alloc(128 * 4);
    int*   bases = (int*)alloc(128 * 4);
    int*   wcur  = (int*)alloc((size_t)na * 4);
    int*   list  = (int*)alloc((size_t)nb * 4);
    float* bpart = (float*)alloc((size_t)ngather * 32 * 4);
    float* apart = (float*)alloc((size_t)nvblk * 32 * 4);
    unsigned short* wfe = (unsigned short*)alloc(24 * 512 * 2);
    unsigned short* wfv = (unsigned short*)alloc(20 * 512 * 2);
    unsigned short* abf = (unsigned short*)alloc((size_t)na * 32 * 2);

    (void)hipMemsetAsync(d_ws, 0, zero_bytes, stream);

    prep_all_kernel<<<(na * 4 + 255) / 256, 256, 0, stream>>>(
        atoms, abf, na * 4, ew1, ew2, ew3, vw1, vw2, vw3, wfe, wfv,
        state, eb1, vb1, ebias, vbias);

    cnt_kernel<<<2048, 256, 0, stream>>>(ba1, cnt, nb);
    scan_block_kernel<<<nscan, SCAN_BLK, 0, stream>>>(cnt, excl, bsums, na);
    scan_tops_kernel<<<1, 128, 0, stream>>>(bsums, bases, nscan);
    wcur_init_kernel<<<(na + 255) / 256, 256, 0, stream>>>(excl, bases, wcur, na);

    phi_e_mfma<<<1024, EBLK, 0, stream>>>(bonds, ba1, ba2, abf, wfe, ebias, eb2, eb3,
                                          bonds_out, wcur, list, nb);

    gather_mean_kernel<<<ngather, 256, 0, stream>>>(bonds_out, list, excl, bases, cnt,
                                                    atoms_out, bpart, na);
    part_reduce_kernel<<<1, 1024, 0, stream>>>(bpart, bsum, ngather);

    phi_v_mfma<<<nvblk, 256, 0, stream>>>(abf, atoms_out, wfv, vbias, vb2, vb3,
                                          apart, na);
    part_reduce_kernel<<<1, 1024, 0, stream>>>(apart, asum, nvblk);

    phi_u_kernel<<<1, 128, 0, stream>>>(bsum, asum, state,
                                        uw1, ub1, uw2, ub2, uw3, ub3,
                                        state_out, 1.0f / (float)nb, 1.0f / (float)na);
}